// Round 16
// baseline (135.649 us; speedup 1.0000x reference)
//
#include <hip/hip_runtime.h>

typedef short bf16x8 __attribute__((ext_vector_type(8)));
typedef _Float16 f16x8 __attribute__((ext_vector_type(8)));
typedef float f32x4 __attribute__((ext_vector_type(4)));
typedef unsigned short u16;
typedef unsigned short u16x4 __attribute__((ext_vector_type(4)));

#define MFMA(a, b, c) __builtin_amdgcn_mfma_f32_16x16x32_bf16(a, b, c, 0, 0, 0)
#define MFMAH(a, b, c) __builtin_amdgcn_mfma_f32_16x16x32_f16(a, b, c, 0, 0, 0)

// ---------- helpers ----------
__device__ __forceinline__ u16 f2b(float f) {
    union { float f; unsigned u; } x{f};
    unsigned r = (x.u + 0x7FFFu + ((x.u >> 16) & 1u)) >> 16;
    return (u16)r;
}
__device__ __forceinline__ float b2f(u16 h) {
    union { unsigned u; float f; } x{((unsigned)h) << 16};
    return x.f;
}
__device__ __forceinline__ u16 f2h(float f) {
    _Float16 h = (_Float16)f;
    return *reinterpret_cast<u16*>(&h);
}
__device__ __forceinline__ float h2f(u16 h) {
    _Float16 v = *reinterpret_cast<_Float16*>(&h);
    return (float)v;
}
__device__ __forceinline__ float red16_sum(float v) {
#pragma unroll
    for (int m = 1; m < 16; m <<= 1) v += __shfl_xor(v, m, 64);
    return v;
}
__device__ __forceinline__ float red16_max(float v) {
#pragma unroll
    for (int m = 1; m < 16; m <<= 1) v = fmaxf(v, __shfl_xor(v, m, 64));
    return v;
}
__device__ __forceinline__ void gl_lds16(const void* g, void* l) {
    __builtin_amdgcn_global_load_lds(
        (const __attribute__((address_space(1))) unsigned int*)(g),
        (__attribute__((address_space(3))) unsigned int*)(l), 16, 0, 0);
}

// dims: B=4, C=64, N=8, V=32, W=32, D=256 ; BN=32, S=1024, tokens M=32768

// ---------- K0: weight convert: gemm weights + fragment-packed proj weights ----------
__global__ __launch_bounds__(256) void wconv_kernel(
    const float* __restrict__ W1, const float* __restrict__ W2,
    const float* __restrict__ Wo, const float* __restrict__ Win,
    const float* __restrict__ Wkv, u16* __restrict__ w1T,
    u16* __restrict__ w2T, u16* __restrict__ woT, u16* __restrict__ wfrag) {
    int id = blockIdx.x * 256 + threadIdx.x;
    if (id < 131072) {                       // W1: (256,512) -> (512,256)
        int n = id >> 8, k = id & 255;
        w1T[id] = f2b(W1[k * 512 + n]);
    } else if (id < 262144) {                // W2: (512,256) -> (256,512)
        int j = id - 131072;
        int n = j >> 9, k = j & 511;
        w2T[j] = f2b(W2[k * 256 + n]);
    } else if (id < 278528) {                // W_out: (256,64) -> (64,256)
        int j = id - 262144;
        int n = j >> 8, k = j & 255;
        woT[j] = f2b(Wo[k * 64 + n]);
    } else if (id < 284672) {                // fragment-packed proj weights (fp16)
        int fid = id - 278528;
        int arr = fid >> 11;                 // 0..2 : q, k, v
        int e = fid & 2047;
        int ntck = e >> 6, ln = e & 63;
        int lr = ln & 15, lg2 = ln >> 4;
        int nt = ntck >> 1, ck = ntck & 1;
        int d = nt * 16 + lr;
#pragma unroll
        for (int j = 0; j < 8; j++) {
            int c = ck * 32 + lg2 * 8 + j;
            float x;
            if (arr == 0)      x = Win[c * 256 + d];
            else if (arr == 1) x = Wkv[c * 512 + d];
            else               x = Wkv[c * 512 + 256 + d];
            wfrag[arr * 16384 + e * 8 + j] = f2h(x);
        }
    }
}

// ---------- K1: MFMA projection + shared LN (fp16 single-pass) ----------
#define PJ_A 0
#define PJ_WREG 16384
#define PJ_WORK 49152
__global__ __launch_bounds__(512, 1) void proj_kernel(
    const float* __restrict__ lf, const float* __restrict__ hf,
    const u16* __restrict__ wqg, const u16* __restrict__ wkg,
    const u16* __restrict__ wvg, const float* __restrict__ gamma,
    const float* __restrict__ beta, u16* __restrict__ qf_,
    u16* __restrict__ kf_, u16* __restrict__ vT) {
    extern __shared__ char sm[];
    const int tid = threadIdx.x;
    const int wave = tid >> 6, lane = tid & 63, lr = lane & 15, lg = lane >> 4;
    const int st = blockIdx.x, bn = blockIdx.y;
    const int b = bn >> 3, n = bn & 7;
    const int s0 = st * 128;
    const size_t baseF = (size_t)b * 524288 + (size_t)n * 1024 + s0;

    float gam[16], bet[16];
#pragma unroll
    for (int nt = 0; nt < 16; nt++) {
        gam[nt] = gamma[nt * 16 + lr];
        bet[nt] = beta[nt * 16 + lr];
    }

    auto stage32 = [&](const float* srcbase, int chalf) {
#pragma unroll
        for (int call = 0; call < 2; call++) {
            int unit = call * 8 + wave;
            int obase = unit << 10;
            int e = unit * 256 + lane * 4;
            int cl = e >> 7, si = e & 127;
            gl_lds16(srcbase + (size_t)(chalf * 32 + cl) * 8192 + si,
                     sm + PJ_WORK + obase);
        }
    };
    auto stageW = [&](const u16* wsrc) {
#pragma unroll
        for (int call = 0; call < 4; call++) {
            int obase = (call * 8 + wave) << 10;
            gl_lds16((const char*)wsrc + obase + lane * 16, sm + PJ_WREG + obase);
        }
    };
    auto buildA = [&](int slotbase) {
        int g = wave >> 1;
        int s = ((wave & 1) << 6) | lane;
        float x[8];
#pragma unroll
        for (int cc = 0; cc < 8; cc++)
            x[cc] = *(const float*)(sm + PJ_WORK + ((g * 8 + cc) << 9) + (s << 2));
        f16x8 ph;
#pragma unroll
        for (int cc = 0; cc < 8; cc++) ph[cc] = (_Float16)x[cc];
        int slp = (slotbase + g) ^ (s & 7);
        *(f16x8*)(sm + PJ_A + (s << 7) + (slp << 4)) = ph;
    };
    auto loadA = [&](f16x8* aF) {
        int tl = wave * 16 + lr;
#pragma unroll
        for (int ck = 0; ck < 2; ck++) {
            int off = (tl << 7) + ((((ck << 2) | lg) ^ (tl & 7)) << 4);
            aF[ck] = *(const f16x8*)(sm + PJ_A + off);
        }
    };
    auto pass1 = [&](const f16x8* aF, f32x4* acc) {
#pragma unroll
        for (int nt = 0; nt < 16; nt++) acc[nt] = (f32x4){0.f, 0.f, 0.f, 0.f};
#pragma unroll
        for (int nt = 0; nt < 16; nt++) {
#pragma unroll
            for (int ck = 0; ck < 2; ck++) {
                int wo = (((nt << 1) | ck) << 10) + (lane << 4);
                f16x8 bh = *(const f16x8*)(sm + PJ_WREG + wo);
                acc[nt] = MFMAH(aF[ck], bh, acc[nt]);
            }
        }
    };
    auto lnstats = [&](const f32x4* acc, float* mean, float* rs) {
#pragma unroll
        for (int r = 0; r < 4; r++) {
            float s1 = 0.f, s2 = 0.f;
#pragma unroll
            for (int nt = 0; nt < 16; nt++) {
                float xv = acc[nt][r];
                s1 += xv; s2 += xv * xv;
            }
            s1 = red16_sum(s1);
            s2 = red16_sum(s2);
            float mn = s1 * (1.f / 256.f);
            float var = s2 * (1.f / 256.f) - mn * mn;
            mean[r] = mn;
            rs[r] = rsqrtf(var + 1e-5f);
        }
    };
    auto emit = [&](const f32x4* acc, const float* mean, const float* rs,
                    u16* dst) {
        char* bw = sm + PJ_WORK + wave * 4096;
        const int gtok = bn * 1024 + s0 + wave * 16;
#pragma unroll
        for (int hh = 0; hh < 2; hh++) {
#pragma unroll
            for (int ntl = 0; ntl < 8; ntl++) {
                int nt = hh * 8 + ntl;
#pragma unroll
                for (int r = 0; r < 4; r++) {
                    float y = (acc[nt][r] - mean[r]) * rs[r] * gam[nt] + bet[nt];
                    int tl = lg * 4 + r;
                    int dl = ntl * 16 + lr;
                    int sl = dl >> 3;
                    *(u16*)(bw + tl * 256 + ((sl ^ ((tl >> 2) & 3)) << 4) +
                            (dl & 7) * 2) = f2h(y);
                }
            }
#pragma unroll
            for (int p = 0; p < 4; p++) {
                int row = lane >> 2, slq = (lane & 3) + p * 4;
                bf16x8 v8 = *(const bf16x8*)(bw + row * 256 +
                                             ((slq ^ ((row >> 2) & 3)) << 4));
                *(bf16x8*)(dst + (size_t)(gtok + row) * 256 + hh * 128 +
                           slq * 8) = v8;
            }
        }
    };

    f32x4 acc[16];
    float mean[4], rs[4];
    f16x8 aF[2];

    // ---- lf -> q ----
    stage32(lf + baseF, 0);  __syncthreads();     // P0
    buildA(0);               __syncthreads();     // P1
    stage32(lf + baseF, 1);
    stageW(wqg);             __syncthreads();     // P2
    buildA(4);               __syncthreads();     // P3
    loadA(aF);
    pass1(aF, acc);
    lnstats(acc, mean, rs);  __syncthreads();     // P4
    stageW(wkg);                                  // P5
    emit(acc, mean, rs, qf_);
    __syncthreads();
    // ---- hf -> k, v ----
    stage32(hf + baseF, 0);  __syncthreads();     // P6
    buildA(0);               __syncthreads();     // P7
    stage32(hf + baseF, 1);  __syncthreads();     // P8
    buildA(4);               __syncthreads();     // P9
    loadA(aF);
    pass1(aF, acc);
    lnstats(acc, mean, rs);  __syncthreads();     // P10
    stageW(wvg);                                  // P11
    emit(acc, mean, rs, kf_);
    __syncthreads();
    pass1(aF, acc);                               // P12: v
#pragma unroll
    for (int nt = 0; nt < 16; nt++) {
        u16x4 pv;
#pragma unroll
        for (int r = 0; r < 4; r++) pv[r] = f2h(acc[nt][r]);
        *(u16x4*)(vT + ((size_t)(bn * 256) + nt * 16 + lr) * 1024 + s0 +
                  wave * 16 + lg * 4) = pv;
    }
}

// ---------- K2: causal flash attention, fp16, split-K, single-buffer/2-blocks ----
// 512 blocks x 512 threads (8 waves). Block b: bn = b&31, strip = 15-(b>>5)
// (LPT). Wave-group 0: k-tiles [0, s+1); group 1: [s+1, 2s+2); fp16 partials
// merged in LDS (flash-decoding). Uniform s+1 iterations.
// SINGLE-BUFFERED K/V (32KB per group) -> LDS 76KB -> 2 blocks/CU =
// 4 waves/SIMD: per-iteration stage latency is covered by the co-resident
// sibling block (TLP), replacing the double-buffer pipeline.
// Per iter: [prev barrier guaranteed no readers] stage(it) -> vmcnt(0) ->
// barrier (all waves' slices landed) -> compute(it) -> barrier -> stage(it+1).
// LDS 76KB: grp0 K@0 V@16K; grp1 K@32K V@48K (combine buffer after loop);
// P @64K (8x1280B; first 512B = m/l exchange after loop).
__global__ __launch_bounds__(512) void attn_kernel(
    const u16* __restrict__ qf_, const u16* __restrict__ kf_,
    const u16* __restrict__ vT, const float* __restrict__ g2,
    const float* __restrict__ b2, u16* __restrict__ lnatt) {
    extern __shared__ char smem[];
    const int tid = threadIdx.x;
    const int wave = tid >> 6, lane = tid & 63, lr = lane & 15, lg = lane >> 4;
    const int grp = wave >> 2, w4 = wave & 3;
    const int b = blockIdx.x;
    const int bn = b & 31;
    const int strip = 15 - (b >> 5);
    const int qr0 = strip * 64 + w4 * 16;
    const int ni = strip + 1;                 // iterations per group
    const int ktbase = grp * ni;
    char* myK = smem + grp * 32768;           // 16KB
    char* myV = myK + 16384;                  // 16KB
    u16* Pw = (u16*)(smem + 65536 + wave * 1280);   // [16 rows][40 u16]

    f16x8 qf[8];
    {
        const size_t off = ((size_t)(bn * 1024 + qr0 + lr)) * 256 + lg * 8;
#pragma unroll
        for (int ck = 0; ck < 8; ck++)
            qf[ck] = *(const f16x8*)(qf_ + off + ck * 32);
    }
    f16x8 onesb;   // B-fragment of ones-column (row-sum via MFMA)
    {
        _Float16 v1 = (lr == 0) ? (_Float16)1.0f : (_Float16)0.0f;
#pragma unroll
        for (int q = 0; q < 8; q++) onesb[q] = v1;
    }

    const int srl = lane >> 5, ss = lane & 31;   // K staging: subrow, slot
    const int vdl = lane >> 2, vg = lane & 3;    // V staging: d-local, group
    auto stage = [&](int kt) {
        const int kv0 = kt << 5;
#pragma unroll
        for (int ii = 0; ii < 4; ii++) {
            int u = w4 * 4 + ii;                   // 0..15, 1KB units
            int r = u * 2 + srl;                   // K row 0..31
            size_t go = (((size_t)((bn << 10) + kv0 + r)) << 8) +
                        (unsigned)((ss ^ (r & 7)) << 3);
            gl_lds16(kf_ + go, myK + u * 1024);
            int d = u * 16 + vdl;                  // V d 0..255
            size_t gv = (((size_t)((bn << 8) + d)) << 10) + kv0 +
                        (unsigned)((vg ^ ((d >> 1) & 3)) << 3);
            gl_lds16(vT + gv, myV + u * 1024);
        }
    };

    f32x4 o[16];
#pragma unroll
    for (int i = 0; i < 16; i++) o[i] = (f32x4){0.f, 0.f, 0.f, 0.f};
    f32x4 ol = (f32x4){0.f, 0.f, 0.f, 0.f};
    float m[4] = {-INFINITY, -INFINITY, -INFINITY, -INFINITY};

    stage(ktbase);
    for (int it = 0; it < ni; it++) {
        asm volatile("s_waitcnt vmcnt(0)" ::: "memory");   // my slices landed
        __builtin_amdgcn_s_barrier();                      // all slices landed
        asm volatile("" ::: "memory");
        const int kt = ktbase + it;
        if ((kt << 5) <= qr0 + 15) {
            f32x4 sc0 = (f32x4){0.f, 0.f, 0.f, 0.f};
            f32x4 sc1 = (f32x4){0.f, 0.f, 0.f, 0.f};
            __builtin_amdgcn_s_setprio(1);
#pragma unroll
            for (int ck = 0; ck < 8; ck++) {
                int sw = ((ck * 4 + lg) ^ (lr & 7)) << 4;
                int a0 = lr * 512 + sw;
                f16x8 k0 = *(const f16x8*)(myK + a0);
                f16x8 k1 = *(const f16x8*)(myK + a0 + 8192);
                sc0 = MFMAH(qf[ck], k0, sc0);
                sc1 = MFMAH(qf[ck], k1, sc1);
            }
            __builtin_amdgcn_s_setprio(0);
            float scl[4];
            const int kvb = kt << 5;
#pragma unroll
            for (int r = 0; r < 4; r++) {
                int qi = qr0 + lg * 4 + r;
                float s0v = (kvb + lr > qi) ? -1e30f : sc0[r];
                float s1v = (kvb + 16 + lr > qi) ? -1e30f : sc1[r];
                float tm = red16_max(fmaxf(s0v, s1v));
                float mn = fmaxf(m[r], tm);
                scl[r] = __expf(m[r] - mn);
                m[r] = mn;
                int row = lg * 4 + r;
                Pw[row * 40 + lr] = f2h(__expf(s0v - mn));
                Pw[row * 40 + 16 + lr] = f2h(__expf(s1v - mn));
            }
#pragma unroll
            for (int f = 0; f < 16; f++) {
                f32x4 t = o[f];
                t[0] *= scl[0]; t[1] *= scl[1]; t[2] *= scl[2]; t[3] *= scl[3];
                o[f] = t;
            }
            ol[0] *= scl[0]; ol[1] *= scl[1]; ol[2] *= scl[2]; ol[3] *= scl[3];
            asm volatile("" ::: "memory");   // order P stores before pa load
            f16x8 pa = *(const f16x8*)((const char*)Pw + lr * 80 + lg * 16);
            __builtin_amdgcn_s_setprio(1);
#pragma unroll
            for (int db = 0; db < 16; db++) {
                int d = db * 16 + lr;
                f16x8 vf = *(const f16x8*)(myV + d * 64 +
                                           ((lg ^ ((lr >> 1) & 3)) << 4));
                o[db] = MFMAH(pa, vf, o[db]);
            }
            ol = MFMAH(pa, onesb, ol);
            __builtin_amdgcn_s_setprio(0);
        }
        __builtin_amdgcn_s_barrier();                      // compute(it) done
        asm volatile("" ::: "memory");
        if (it + 1 < ni) stage(ktbase + it + 1);           // overwrite safe
    }
    __syncthreads();   // loop done: protects combine's reuse of grp1 K/V LDS
    float lsum[4];
#pragma unroll
    for (int r = 0; r < 4; r++) lsum[r] = __shfl(ol[r], lane & 48, 64);

    // ---- flash-decoding combine: grp1 -> LDS (fp16 partials), grp0 merges ----
    char* cb = smem + 32768;                 // grp1 K/V region: 4 x 8KB
    float* mlb = (float*)(smem + 65536);     // 64 rows x {m,l} (P region dead)
    if (grp == 1) {
        char* po = cb + w4 * 8192;
#pragma unroll
        for (int f = 0; f < 16; f++) {
            u16x4 ph;
#pragma unroll
            for (int r = 0; r < 4; r++) ph[r] = f2h(o[f][r]);
            *(u16x4*)(po + (f * 16 + lr) * 32 + lg * 8) = ph;
        }
        if (lr == 0) {
#pragma unroll
            for (int r = 0; r < 4; r++) {
                int row = lg * 4 + r;
                mlb[(w4 * 16 + row) * 2] = m[r];
                mlb[(w4 * 16 + row) * 2 + 1] = lsum[r];
            }
        }
    }
    __syncthreads();
    if (grp == 0) {
        const char* po = cb + w4 * 8192;
        float e0[4], e1[4], linv[4];
#pragma unroll
        for (int r = 0; r < 4; r++) {
            int row = lg * 4 + r;
            float m1 = mlb[(w4 * 16 + row) * 2];
            float l1 = mlb[(w4 * 16 + row) * 2 + 1];
            float ms = fmaxf(m[r], m1);
            e0[r] = __expf(m[r] - ms);
            e1[r] = __expf(m1 - ms);
            linv[r] = 1.f / (lsum[r] * e0[r] + l1 * e1[r]);
        }
#pragma unroll
        for (int f = 0; f < 16; f++) {
            u16x4 ph = *(const u16x4*)(po + (f * 16 + lr) * 32 + lg * 8);
#pragma unroll
            for (int r = 0; r < 4; r++)
                o[f][r] = (o[f][r] * e0[r] + h2f(ph[r]) * e1[r]) * linv[r];
        }
        float gv[16], bv[16];
#pragma unroll
        for (int f = 0; f < 16; f++) {
            gv[f] = g2[f * 16 + lr];
            bv[f] = b2[f * 16 + lr];
        }
#pragma unroll
        for (int r = 0; r < 4; r++) {
            float s1 = 0.f, s2 = 0.f;
#pragma unroll
            for (int f = 0; f < 16; f++) {
                float x = o[f][r];
                s1 += x; s2 += x * x;
            }
            s1 = red16_sum(s1);
            s2 = red16_sum(s2);
            float mean = s1 * (1.f / 256.f);
            float var = s2 * (1.f / 256.f) - mean * mean;
            float rsv = rsqrtf(var + 1e-5f);
            size_t row = (size_t)(bn * 1024 + qr0 + lg * 4 + r) * 256;
#pragma unroll
            for (int f = 0; f < 16; f++)
                lnatt[row + f * 16 + lr] =
                    f2b((o[f][r] - mean) * rsv * gv[f] + bv[f]);
        }
    }
}

// ---------- K3/K4/K5: LDS-staged GEMM, A(MxK) bf16, BT(NxK) bf16 ----------
template <int K, int NB, int MODE>
__global__ __launch_bounds__(512) void gemmB_kernel(
    const u16* __restrict__ A, const u16* __restrict__ BT,
    u16* __restrict__ outb, const u16* __restrict__ vTr,
    float* __restrict__ outf, int ldOut) {
    extern __shared__ char bsm[];
    const int tid = threadIdx.x;
    const int wave = tid >> 6, lane = tid & 63, lr = lane & 15, lg = lane >> 4;
    constexpr int K2 = K * 2;           // bytes per B column
    constexpr int BN = NB * 16;
    constexpr int TILE = BN * K2;
    const int m0 = blockIdx.x * 128 + wave * 16;
    const int n0 = blockIdx.y * BN;
    {
        const char* bsrc = (const char*)(BT + (size_t)n0 * K);
        constexpr int ITER = TILE / (512 * 16);
#pragma unroll
        for (int it = 0; it < ITER; it++) {
            int o = (it * 512 + tid) * 16;
            int col = o / K2;
            int slot = (o % K2) >> 4;
            int src = col * K2 + ((slot ^ (col & 7)) << 4);
            gl_lds16(bsrc + src, bsm + o);
        }
    }
    __syncthreads();
    f32x4 acc[NB];
#pragma unroll
    for (int nb = 0; nb < NB; nb++) acc[nb] = (f32x4){0.f, 0.f, 0.f, 0.f};
    const u16* ap = A + (size_t)(m0 + lr) * K + lg * 8;
#pragma unroll
    for (int kc = 0; kc < K; kc += 32) {
        bf16x8 a = *(const bf16x8*)(ap + kc);
        int ks = (kc >> 3) + lg;
#pragma unroll
        for (int nb = 0; nb < NB; nb++) {
            int c = nb * 16 + lr;
            bf16x8 bv = *(const bf16x8*)(bsm + c * K2 + ((ks ^ (c & 7)) << 4));
            acc[nb] = MFMA(a, bv, acc[nb]);
        }
    }
    const int g = m0 + lg * 4;
    if (MODE == 0) {
#pragma unroll
        for (int nb = 0; nb < NB; nb++)
#pragma unroll
            for (int r = 0; r < 4; r++)
                outb[(size_t)(g + r) * ldOut + n0 + nb * 16 + lr] =
                    f2b(fmaxf(acc[nb][r], 0.f));
    } else if (MODE == 1) {
        int bn = g >> 10, s = g & 1023;
#pragma unroll
        for (int nb = 0; nb < NB; nb++) {
            int dd = n0 + nb * 16 + lr;
            u16x4 vv = *(const u16x4*)(vTr + ((size_t)bn * 256 + dd) * 1024 + s);
#pragma unroll
            for (int r = 0; r < 4; r++)
                outb[(size_t)(g + r) * 256 + dd] = f2b(acc[nb][r] + h2f(vv[r]));
        }
    } else {
        int bn = g >> 10, s = g & 1023;
        int bb = bn >> 3, nn = bn & 7;
#pragma unroll
        for (int nb = 0; nb < NB; nb++) {
            int cc = n0 + nb * 16 + lr;
            *(f32x4*)(outf + (size_t)bb * 524288 + (size_t)cc * 8192 +
                      (size_t)nn * 1024 + s) = acc[nb];
        }
    }
}

extern "C" void kernel_launch(void* const* d_in, const int* in_sizes, int n_in,
                              void* d_out, int out_size, void* d_ws, size_t ws_size,
                              hipStream_t stream) {
    const float* lf    = (const float*)d_in[0];
    const float* hf    = (const float*)d_in[1];
    const float* Win   = (const float*)d_in[2];
    const float* Wkv   = (const float*)d_in[3];
    const float* gamma = (const float*)d_in[4];
    const float* beta  = (const float*)d_in[5];
    const float* g2    = (const float*)d_in[6];
    const float* b2    = (const float*)d_in[7];
    const float* W1    = (const float*)d_in[8];
    const float* W2    = (const float*)d_in[9];
    const float* Wo    = (const float*)d_in[10];
    float* out = (float*)d_out;

    char* w = (char*)d_ws;
    const size_t MB16 = 16777216;
    u16* qf  = (u16*)(w);                        // fp16 q (16.78 MB)
    u16* kf  = (u16*)(w + MB16);                 // fp16 k
    u16* vT  = (u16*)(w + 2 * MB16);             // fp16 v, (BN,256,1024)
    u16* hb  = (u16*)(w + 3 * MB16);             // bf16 FFN hidden (33.55 MB)
    u16* w1T = (u16*)(w + 3 * MB16 + 33554432);
    u16* w2T = w1T + 131072;
    u16* woT = w2T + 131072;
    u16* wfrag = woT + 16384;                    // 3 x 16384 u16 (fp16)
    u16* wqg = wfrag;
    u16* wkg = wfrag + 16384;
    u16* wvg = wfrag + 32768;
    u16* lnatt = qf;   // reuse: q rows consumed before LN write (bf16)
    u16* epib  = kf;   // reuse: k dead after attention (bf16)

    wconv_kernel<<<dim3(1136), dim3(256), 0, stream>>>(W1, W2, Wo, Win, Wkv,
                                                       w1T, w2T, woT, wfrag);
    proj_kernel<<<dim3(8, 32), dim3(512), 81920, stream>>>(
        lf, hf, wqg, wkg, wvg, gamma, beta, qf, kf, vT);
    attn_kernel<<<dim3(512), dim3(512), 75776, stream>>>(qf, kf, vT, g2, b2,
                                                         lnatt);
    gemmB_kernel<256, 8, 0><<<dim3(256, 4), dim3(512), 65536, stream>>>(
        lnatt, w1T, hb, nullptr, nullptr, 512);
    gemmB_kernel<512, 8, 1><<<dim3(256, 2), dim3(512), 131072, stream>>>(
        hb, w2T, epib, vT, nullptr, 256);
    gemmB_kernel<256, 4, 2><<<dim3(256, 1), dim3(512), 32768, stream>>>(
        epib, woT, nullptr, nullptr, out, 64);
}

// Round 17
// 132.622 us; speedup vs baseline: 1.0228x; 1.0228x over previous
//
#include <hip/hip_runtime.h>

typedef short bf16x8 __attribute__((ext_vector_type(8)));
typedef _Float16 f16x8 __attribute__((ext_vector_type(8)));
typedef float f32x4 __attribute__((ext_vector_type(4)));
typedef unsigned short u16;
typedef unsigned short u16x4 __attribute__((ext_vector_type(4)));

#define MFMA(a, b, c) __builtin_amdgcn_mfma_f32_16x16x32_bf16(a, b, c, 0, 0, 0)
#define MFMAH(a, b, c) __builtin_amdgcn_mfma_f32_16x16x32_f16(a, b, c, 0, 0, 0)

// ---------- helpers ----------
__device__ __forceinline__ u16 f2b(float f) {
    union { float f; unsigned u; } x{f};
    unsigned r = (x.u + 0x7FFFu + ((x.u >> 16) & 1u)) >> 16;
    return (u16)r;
}
__device__ __forceinline__ float b2f(u16 h) {
    union { unsigned u; float f; } x{((unsigned)h) << 16};
    return x.f;
}
__device__ __forceinline__ u16 f2h(float f) {
    _Float16 h = (_Float16)f;
    return *reinterpret_cast<u16*>(&h);
}
__device__ __forceinline__ float h2f(u16 h) {
    _Float16 v = *reinterpret_cast<_Float16*>(&h);
    return (float)v;
}
__device__ __forceinline__ float red16_sum(float v) {
#pragma unroll
    for (int m = 1; m < 16; m <<= 1) v += __shfl_xor(v, m, 64);
    return v;
}
__device__ __forceinline__ float red16_max(float v) {
#pragma unroll
    for (int m = 1; m < 16; m <<= 1) v = fmaxf(v, __shfl_xor(v, m, 64));
    return v;
}
__device__ __forceinline__ void gl_lds16(const void* g, void* l) {
    __builtin_amdgcn_global_load_lds(
        (const __attribute__((address_space(1))) unsigned int*)(g),
        (__attribute__((address_space(3))) unsigned int*)(l), 16, 0, 0);
}

// dims: B=4, C=64, N=8, V=32, W=32, D=256 ; BN=32, S=1024, tokens M=32768

// ---------- K0: weight convert: gemm weights + fragment-packed proj weights ----------
__global__ __launch_bounds__(256) void wconv_kernel(
    const float* __restrict__ W1, const float* __restrict__ W2,
    const float* __restrict__ Wo, const float* __restrict__ Win,
    const float* __restrict__ Wkv, u16* __restrict__ w1T,
    u16* __restrict__ w2T, u16* __restrict__ woT, u16* __restrict__ wfrag) {
    int id = blockIdx.x * 256 + threadIdx.x;
    if (id < 131072) {                       // W1: (256,512) -> (512,256)
        int n = id >> 8, k = id & 255;
        w1T[id] = f2b(W1[k * 512 + n]);
    } else if (id < 262144) {                // W2: (512,256) -> (256,512)
        int j = id - 131072;
        int n = j >> 9, k = j & 511;
        w2T[j] = f2b(W2[k * 256 + n]);
    } else if (id < 278528) {                // W_out: (256,64) -> (64,256)
        int j = id - 262144;
        int n = j >> 8, k = j & 255;
        woT[j] = f2b(Wo[k * 64 + n]);
    } else if (id < 284672) {                // fragment-packed proj weights (fp16)
        int fid = id - 278528;
        int arr = fid >> 11;                 // 0..2 : q, k, v
        int e = fid & 2047;
        int ntck = e >> 6, ln = e & 63;
        int lr = ln & 15, lg2 = ln >> 4;
        int nt = ntck >> 1, ck = ntck & 1;
        int d = nt * 16 + lr;
#pragma unroll
        for (int j = 0; j < 8; j++) {
            int c = ck * 32 + lg2 * 8 + j;
            float x;
            if (arr == 0)      x = Win[c * 256 + d];
            else if (arr == 1) x = Wkv[c * 512 + d];
            else               x = Wkv[c * 512 + 256 + d];
            wfrag[arr * 16384 + e * 8 + j] = f2h(x);
        }
    }
}

// ---------- K1: MFMA projection + shared LN (fp16 single-pass) ----------
#define PJ_A 0
#define PJ_WREG 16384
#define PJ_WORK 49152
__global__ __launch_bounds__(512, 1) void proj_kernel(
    const float* __restrict__ lf, const float* __restrict__ hf,
    const u16* __restrict__ wqg, const u16* __restrict__ wkg,
    const u16* __restrict__ wvg, const float* __restrict__ gamma,
    const float* __restrict__ beta, u16* __restrict__ qf_,
    u16* __restrict__ kf_, u16* __restrict__ vT) {
    extern __shared__ char sm[];
    const int tid = threadIdx.x;
    const int wave = tid >> 6, lane = tid & 63, lr = lane & 15, lg = lane >> 4;
    const int st = blockIdx.x, bn = blockIdx.y;
    const int b = bn >> 3, n = bn & 7;
    const int s0 = st * 128;
    const size_t baseF = (size_t)b * 524288 + (size_t)n * 1024 + s0;

    float gam[16], bet[16];
#pragma unroll
    for (int nt = 0; nt < 16; nt++) {
        gam[nt] = gamma[nt * 16 + lr];
        bet[nt] = beta[nt * 16 + lr];
    }

    auto stage32 = [&](const float* srcbase, int chalf) {
#pragma unroll
        for (int call = 0; call < 2; call++) {
            int unit = call * 8 + wave;
            int obase = unit << 10;
            int e = unit * 256 + lane * 4;
            int cl = e >> 7, si = e & 127;
            gl_lds16(srcbase + (size_t)(chalf * 32 + cl) * 8192 + si,
                     sm + PJ_WORK + obase);
        }
    };
    auto stageW = [&](const u16* wsrc) {
#pragma unroll
        for (int call = 0; call < 4; call++) {
            int obase = (call * 8 + wave) << 10;
            gl_lds16((const char*)wsrc + obase + lane * 16, sm + PJ_WREG + obase);
        }
    };
    auto buildA = [&](int slotbase) {
        int g = wave >> 1;
        int s = ((wave & 1) << 6) | lane;
        float x[8];
#pragma unroll
        for (int cc = 0; cc < 8; cc++)
            x[cc] = *(const float*)(sm + PJ_WORK + ((g * 8 + cc) << 9) + (s << 2));
        f16x8 ph;
#pragma unroll
        for (int cc = 0; cc < 8; cc++) ph[cc] = (_Float16)x[cc];
        int slp = (slotbase + g) ^ (s & 7);
        *(f16x8*)(sm + PJ_A + (s << 7) + (slp << 4)) = ph;
    };
    auto loadA = [&](f16x8* aF) {
        int tl = wave * 16 + lr;
#pragma unroll
        for (int ck = 0; ck < 2; ck++) {
            int off = (tl << 7) + ((((ck << 2) | lg) ^ (tl & 7)) << 4);
            aF[ck] = *(const f16x8*)(sm + PJ_A + off);
        }
    };
    auto pass1 = [&](const f16x8* aF, f32x4* acc) {
#pragma unroll
        for (int nt = 0; nt < 16; nt++) acc[nt] = (f32x4){0.f, 0.f, 0.f, 0.f};
#pragma unroll
        for (int nt = 0; nt < 16; nt++) {
#pragma unroll
            for (int ck = 0; ck < 2; ck++) {
                int wo = (((nt << 1) | ck) << 10) + (lane << 4);
                f16x8 bh = *(const f16x8*)(sm + PJ_WREG + wo);
                acc[nt] = MFMAH(aF[ck], bh, acc[nt]);
            }
        }
    };
    auto lnstats = [&](const f32x4* acc, float* mean, float* rs) {
#pragma unroll
        for (int r = 0; r < 4; r++) {
            float s1 = 0.f, s2 = 0.f;
#pragma unroll
            for (int nt = 0; nt < 16; nt++) {
                float xv = acc[nt][r];
                s1 += xv; s2 += xv * xv;
            }
            s1 = red16_sum(s1);
            s2 = red16_sum(s2);
            float mn = s1 * (1.f / 256.f);
            float var = s2 * (1.f / 256.f) - mn * mn;
            mean[r] = mn;
            rs[r] = rsqrtf(var + 1e-5f);
        }
    };
    auto emit = [&](const f32x4* acc, const float* mean, const float* rs,
                    u16* dst) {
        char* bw = sm + PJ_WORK + wave * 4096;
        const int gtok = bn * 1024 + s0 + wave * 16;
#pragma unroll
        for (int hh = 0; hh < 2; hh++) {
#pragma unroll
            for (int ntl = 0; ntl < 8; ntl++) {
                int nt = hh * 8 + ntl;
#pragma unroll
                for (int r = 0; r < 4; r++) {
                    float y = (acc[nt][r] - mean[r]) * rs[r] * gam[nt] + bet[nt];
                    int tl = lg * 4 + r;
                    int dl = ntl * 16 + lr;
                    int sl = dl >> 3;
                    *(u16*)(bw + tl * 256 + ((sl ^ ((tl >> 2) & 3)) << 4) +
                            (dl & 7) * 2) = f2h(y);
                }
            }
#pragma unroll
            for (int p = 0; p < 4; p++) {
                int row = lane >> 2, slq = (lane & 3) + p * 4;
                bf16x8 v8 = *(const bf16x8*)(bw + row * 256 +
                                             ((slq ^ ((row >> 2) & 3)) << 4));
                *(bf16x8*)(dst + (size_t)(gtok + row) * 256 + hh * 128 +
                           slq * 8) = v8;
            }
        }
    };

    f32x4 acc[16];
    float mean[4], rs[4];
    f16x8 aF[2];

    // ---- lf -> q ----
    stage32(lf + baseF, 0);  __syncthreads();     // P0
    buildA(0);               __syncthreads();     // P1
    stage32(lf + baseF, 1);
    stageW(wqg);             __syncthreads();     // P2
    buildA(4);               __syncthreads();     // P3
    loadA(aF);
    pass1(aF, acc);
    lnstats(acc, mean, rs);  __syncthreads();     // P4
    stageW(wkg);                                  // P5
    emit(acc, mean, rs, qf_);
    __syncthreads();
    // ---- hf -> k, v ----
    stage32(hf + baseF, 0);  __syncthreads();     // P6
    buildA(0);               __syncthreads();     // P7
    stage32(hf + baseF, 1);  __syncthreads();     // P8
    buildA(4);               __syncthreads();     // P9
    loadA(aF);
    pass1(aF, acc);
    lnstats(acc, mean, rs);  __syncthreads();     // P10
    stageW(wvg);                                  // P11
    emit(acc, mean, rs, kf_);
    __syncthreads();
    pass1(aF, acc);                               // P12: v
#pragma unroll
    for (int nt = 0; nt < 16; nt++) {
        u16x4 pv;
#pragma unroll
        for (int r = 0; r < 4; r++) pv[r] = f2h(acc[nt][r]);
        *(u16x4*)(vT + ((size_t)(bn * 256) + nt * 16 + lr) * 1024 + s0 +
                  wave * 16 + lg * 4) = pv;
    }
}

// ---------- K2: causal flash attention, fp16, intra-block split-K ----------
// R15 configuration (race-free, 60.1us measured) — restored verbatim.
// 512 blocks x 512 threads (8 waves). Block b: bn = b&31, strip = 15-(b>>5)
// (LPT). Wave-group 0: k-tiles [0, s+1); group 1: [s+1, 2s+2); partials
// merged in LDS (flash-decoding). Uniform s+1 iterations.
// Per iter: vmcnt(0) [stage(it) landed; latency hid under compute(it-1)]
// -> barrier [all compute(it-1) reads retired] -> stage(it+1) [lands during
// compute(it)] -> compute(it).  WAR+RAW closed.
// LDS 138KB: grp0 K/V dbuf @0 (64KB), grp1 @65536 (64KB; o-partial buffer
// after loop), P @131072 (8x1280B; first 512B = m/l exchange after loop).
__global__ __launch_bounds__(512) void attn_kernel(
    const u16* __restrict__ qf_, const u16* __restrict__ kf_,
    const u16* __restrict__ vT, const float* __restrict__ g2,
    const float* __restrict__ b2, u16* __restrict__ lnatt) {
    extern __shared__ char smem[];
    const int tid = threadIdx.x;
    const int wave = tid >> 6, lane = tid & 63, lr = lane & 15, lg = lane >> 4;
    const int grp = wave >> 2, w4 = wave & 3;
    const int b = blockIdx.x;
    const int bn = b & 31;
    const int strip = 15 - (b >> 5);
    const int qr0 = strip * 64 + w4 * 16;
    const int ni = strip + 1;                 // iterations per group
    const int ktbase = grp * ni;
    char* myK = smem + grp * 65536;           // 2 x 16KB dbuf
    char* myV = smem + grp * 65536 + 32768;   // 2 x 16KB dbuf
    u16* Pw = (u16*)(smem + 131072 + wave * 1280);   // [16 rows][40 u16]

    f16x8 qf[8];
    {
        const size_t off = ((size_t)(bn * 1024 + qr0 + lr)) * 256 + lg * 8;
#pragma unroll
        for (int ck = 0; ck < 8; ck++)
            qf[ck] = *(const f16x8*)(qf_ + off + ck * 32);
    }
    f16x8 onesb;   // B-fragment of ones-column (row-sum via MFMA)
    {
        _Float16 v1 = (lr == 0) ? (_Float16)1.0f : (_Float16)0.0f;
#pragma unroll
        for (int q = 0; q < 8; q++) onesb[q] = v1;
    }

    const int srl = lane >> 5, ss = lane & 31;   // K staging: subrow, slot
    const int vdl = lane >> 2, vg = lane & 3;    // V staging: d-local, group
    auto stage = [&](int buf, int kt) {
        const int kv0 = kt << 5;
        char* baseK = myK + buf * 16384;
        char* baseV = myV + buf * 16384;
#pragma unroll
        for (int ii = 0; ii < 4; ii++) {
            int u = w4 * 4 + ii;                   // 0..15, 1KB units
            int r = u * 2 + srl;                   // K row 0..31
            size_t go = (((size_t)((bn << 10) + kv0 + r)) << 8) +
                        (unsigned)((ss ^ (r & 7)) << 3);
            gl_lds16(kf_ + go, baseK + u * 1024);
            int d = u * 16 + vdl;                  // V d 0..255
            size_t gv = (((size_t)((bn << 8) + d)) << 10) + kv0 +
                        (unsigned)((vg ^ ((d >> 1) & 3)) << 3);
            gl_lds16(vT + gv, baseV + u * 1024);
        }
    };

    f32x4 o[16];
#pragma unroll
    for (int i = 0; i < 16; i++) o[i] = (f32x4){0.f, 0.f, 0.f, 0.f};
    f32x4 ol = (f32x4){0.f, 0.f, 0.f, 0.f};
    float m[4] = {-INFINITY, -INFINITY, -INFINITY, -INFINITY};

    stage(0, ktbase);
    for (int it = 0; it < ni; it++) {
        const int cur = it & 1;
        asm volatile("s_waitcnt vmcnt(0)" ::: "memory");   // stage(it) landed
        __builtin_amdgcn_s_barrier();                      // compute(it-1) done
        asm volatile("" ::: "memory");
        if (it + 1 < ni) stage(cur ^ 1, ktbase + it + 1);  // overlaps compute(it)
        const int kt = ktbase + it;
        if ((kt << 5) <= qr0 + 15) {
            const char* kb = myK + cur * 16384;
            f32x4 sc0 = (f32x4){0.f, 0.f, 0.f, 0.f};
            f32x4 sc1 = (f32x4){0.f, 0.f, 0.f, 0.f};
            __builtin_amdgcn_s_setprio(1);
#pragma unroll
            for (int ck = 0; ck < 8; ck++) {
                int sw = ((ck * 4 + lg) ^ (lr & 7)) << 4;
                int a0 = lr * 512 + sw;
                f16x8 k0 = *(const f16x8*)(kb + a0);
                f16x8 k1 = *(const f16x8*)(kb + a0 + 8192);
                sc0 = MFMAH(qf[ck], k0, sc0);
                sc1 = MFMAH(qf[ck], k1, sc1);
            }
            __builtin_amdgcn_s_setprio(0);
            float scl[4];
            const int kvb = kt << 5;
#pragma unroll
            for (int r = 0; r < 4; r++) {
                int qi = qr0 + lg * 4 + r;
                float s0v = (kvb + lr > qi) ? -1e30f : sc0[r];
                float s1v = (kvb + 16 + lr > qi) ? -1e30f : sc1[r];
                float tm = red16_max(fmaxf(s0v, s1v));
                float mn = fmaxf(m[r], tm);
                scl[r] = __expf(m[r] - mn);
                m[r] = mn;
                int row = lg * 4 + r;
                Pw[row * 40 + lr] = f2h(__expf(s0v - mn));
                Pw[row * 40 + 16 + lr] = f2h(__expf(s1v - mn));
            }
#pragma unroll
            for (int f = 0; f < 16; f++) {
                f32x4 t = o[f];
                t[0] *= scl[0]; t[1] *= scl[1]; t[2] *= scl[2]; t[3] *= scl[3];
                o[f] = t;
            }
            ol[0] *= scl[0]; ol[1] *= scl[1]; ol[2] *= scl[2]; ol[3] *= scl[3];
            asm volatile("" ::: "memory");   // order P stores before pa load
            f16x8 pa = *(const f16x8*)((const char*)Pw + lr * 80 + lg * 16);
            const char* vb = myV + cur * 16384;
            __builtin_amdgcn_s_setprio(1);
#pragma unroll
            for (int db = 0; db < 16; db++) {
                int d = db * 16 + lr;
                f16x8 vf = *(const f16x8*)(vb + d * 64 +
                                           ((lg ^ ((lr >> 1) & 3)) << 4));
                o[db] = MFMAH(pa, vf, o[db]);
            }
            ol = MFMAH(pa, onesb, ol);
            __builtin_amdgcn_s_setprio(0);
        }
    }
    __syncthreads();   // loop done: protects combine's reuse of grp1 K/V LDS
    float lsum[4];
#pragma unroll
    for (int r = 0; r < 4; r++) lsum[r] = __shfl(ol[r], lane & 48, 64);

    // ---- flash-decoding combine: grp1 -> LDS, grp0 merges ----
    char* cb = smem + 65536;                 // 4 pairs x 16KB: [col][row] f32
    float* mlb = (float*)(smem + 131072);    // 64 rows x {m,l} (P region dead)
    if (grp == 1) {
        char* po = cb + w4 * 16384;
#pragma unroll
        for (int f = 0; f < 16; f++)
            *(f32x4*)(po + (f * 16 + lr) * 64 + lg * 16) = o[f];
        if (lr == 0) {
#pragma unroll
            for (int r = 0; r < 4; r++) {
                int row = lg * 4 + r;
                mlb[(w4 * 16 + row) * 2] = m[r];
                mlb[(w4 * 16 + row) * 2 + 1] = lsum[r];
            }
        }
    }
    __syncthreads();
    if (grp == 0) {
        const char* po = cb + w4 * 16384;
        float e0[4], e1[4], linv[4];
#pragma unroll
        for (int r = 0; r < 4; r++) {
            int row = lg * 4 + r;
            float m1 = mlb[(w4 * 16 + row) * 2];
            float l1 = mlb[(w4 * 16 + row) * 2 + 1];
            float ms = fmaxf(m[r], m1);
            e0[r] = __expf(m[r] - ms);
            e1[r] = __expf(m1 - ms);
            linv[r] = 1.f / (lsum[r] * e0[r] + l1 * e1[r]);
        }
#pragma unroll
        for (int f = 0; f < 16; f++) {
            f32x4 o1 = *(const f32x4*)(po + (f * 16 + lr) * 64 + lg * 16);
#pragma unroll
            for (int r = 0; r < 4; r++)
                o[f][r] = (o[f][r] * e0[r] + o1[r] * e1[r]) * linv[r];
        }
        float gv[16], bv[16];
#pragma unroll
        for (int f = 0; f < 16; f++) {
            gv[f] = g2[f * 16 + lr];
            bv[f] = b2[f * 16 + lr];
        }
#pragma unroll
        for (int r = 0; r < 4; r++) {
            float s1 = 0.f, s2 = 0.f;
#pragma unroll
            for (int f = 0; f < 16; f++) {
                float x = o[f][r];
                s1 += x; s2 += x * x;
            }
            s1 = red16_sum(s1);
            s2 = red16_sum(s2);
            float mean = s1 * (1.f / 256.f);
            float var = s2 * (1.f / 256.f) - mean * mean;
            float rsv = rsqrtf(var + 1e-5f);
            size_t row = (size_t)(bn * 1024 + qr0 + lg * 4 + r) * 256;
#pragma unroll
            for (int f = 0; f < 16; f++)
                lnatt[row + f * 16 + lr] =
                    f2b((o[f][r] - mean) * rsv * gv[f] + bv[f]);
        }
    }
}

// ---------- K3/K4/K5: LDS-staged GEMM, A(MxK) bf16, BT(NxK) bf16 ----------
template <int K, int NB, int MODE>
__global__ __launch_bounds__(512) void gemmB_kernel(
    const u16* __restrict__ A, const u16* __restrict__ BT,
    u16* __restrict__ outb, const u16* __restrict__ vTr,
    float* __restrict__ outf, int ldOut) {
    extern __shared__ char bsm[];
    const int tid = threadIdx.x;
    const int wave = tid >> 6, lane = tid & 63, lr = lane & 15, lg = lane >> 4;
    constexpr int K2 = K * 2;           // bytes per B column
    constexpr int BN = NB * 16;
    constexpr int TILE = BN * K2;
    const int m0 = blockIdx.x * 128 + wave * 16;
    const int n0 = blockIdx.y * BN;
    {
        const char* bsrc = (const char*)(BT + (size_t)n0 * K);
        constexpr int ITER = TILE / (512 * 16);
#pragma unroll
        for (int it = 0; it < ITER; it++) {
            int o = (it * 512 + tid) * 16;
            int col = o / K2;
            int slot = (o % K2) >> 4;
            int src = col * K2 + ((slot ^ (col & 7)) << 4);
            gl_lds16(bsrc + src, bsm + o);
        }
    }
    __syncthreads();
    f32x4 acc[NB];
#pragma unroll
    for (int nb = 0; nb < NB; nb++) acc[nb] = (f32x4){0.f, 0.f, 0.f, 0.f};
    const u16* ap = A + (size_t)(m0 + lr) * K + lg * 8;
#pragma unroll
    for (int kc = 0; kc < K; kc += 32) {
        bf16x8 a = *(const bf16x8*)(ap + kc);
        int ks = (kc >> 3) + lg;
#pragma unroll
        for (int nb = 0; nb < NB; nb++) {
            int c = nb * 16 + lr;
            bf16x8 bv = *(const bf16x8*)(bsm + c * K2 + ((ks ^ (c & 7)) << 4));
            acc[nb] = MFMA(a, bv, acc[nb]);
        }
    }
    const int g = m0 + lg * 4;
    if (MODE == 0) {
#pragma unroll
        for (int nb = 0; nb < NB; nb++)
#pragma unroll
            for (int r = 0; r < 4; r++)
                outb[(size_t)(g + r) * ldOut + n0 + nb * 16 + lr] =
                    f2b(fmaxf(acc[nb][r], 0.f));
    } else if (MODE == 1) {
        int bn = g >> 10, s = g & 1023;
#pragma unroll
        for (int nb = 0; nb < NB; nb++) {
            int dd = n0 + nb * 16 + lr;
            u16x4 vv = *(const u16x4*)(vTr + ((size_t)bn * 256 + dd) * 1024 + s);
#pragma unroll
            for (int r = 0; r < 4; r++)
                outb[(size_t)(g + r) * 256 + dd] = f2b(acc[nb][r] + h2f(vv[r]));
        }
    } else {
        int bn = g >> 10, s = g & 1023;
        int bb = bn >> 3, nn = bn & 7;
#pragma unroll
        for (int nb = 0; nb < NB; nb++) {
            int cc = n0 + nb * 16 + lr;
            *(f32x4*)(outf + (size_t)bb * 524288 + (size_t)cc * 8192 +
                      (size_t)nn * 1024 + s) = acc[nb];
        }
    }
}

extern "C" void kernel_launch(void* const* d_in, const int* in_sizes, int n_in,
                              void* d_out, int out_size, void* d_ws, size_t ws_size,
                              hipStream_t stream) {
    const float* lf    = (const float*)d_in[0];
    const float* hf    = (const float*)d_in[1];
    const float* Win   = (const float*)d_in[2];
    const float* Wkv   = (const float*)d_in[3];
    const float* gamma = (const float*)d_in[4];
    const float* beta  = (const float*)d_in[5];
    const float* g2    = (const float*)d_in[6];
    const float* b2    = (const float*)d_in[7];
    const float* W1    = (const float*)d_in[8];
    const float* W2    = (const float*)d_in[9];
    const float* Wo    = (const float*)d_in[10];
    float* out = (float*)d_out;

    char* w = (char*)d_ws;
    const size_t MB16 = 16777216;
    u16* qf  = (u16*)(w);                        // fp16 q (16.78 MB)
    u16* kf  = (u16*)(w + MB16);                 // fp16 k
    u16* vT  = (u16*)(w + 2 * MB16);             // fp16 v, (BN,256,1024)
    u16* hb  = (u16*)(w + 3 * MB16);             // bf16 FFN hidden (33.55 MB)
    u16* w1T = (u16*)(w + 3 * MB16 + 33554432);
    u16* w2T = w1T + 131072;
    u16* woT = w2T + 131072;
    u16* wfrag = woT + 16384;                    // 3 x 16384 u16 (fp16)
    u16* wqg = wfrag;
    u16* wkg = wfrag + 16384;
    u16* wvg = wfrag + 32768;
    u16* lnatt = qf;   // reuse: q rows consumed before LN write (bf16)
    u16* epib  = kf;   // reuse: k dead after attention (bf16)

    wconv_kernel<<<dim3(1136), dim3(256), 0, stream>>>(W1, W2, Wo, Win, Wkv,
                                                       w1T, w2T, woT, wfrag);
    proj_kernel<<<dim3(8, 32), dim3(512), 81920, stream>>>(
        lf, hf, wqg, wkg, wvg, gamma, beta, qf, kf, vT);
    attn_kernel<<<dim3(512), dim3(512), 141312, stream>>>(qf, kf, vT, g2, b2,
                                                          lnatt);
    gemmB_kernel<256, 8, 0><<<dim3(256, 4), dim3(512), 65536, stream>>>(
        lnatt, w1T, hb, nullptr, nullptr, 512);
    gemmB_kernel<512, 4, 1><<<dim3(256, 4), dim3(512), 65536, stream>>>(
        hb, w2T, epib, vT, nullptr, 256);
    gemmB_kernel<256, 4, 2><<<dim3(256, 1), dim3(512), 32768, stream>>>(
        epib, woT, nullptr, nullptr, out, 64);
}

// Round 18
// 132.574 us; speedup vs baseline: 1.0232x; 1.0004x over previous
//
#include <hip/hip_runtime.h>

typedef short bf16x8 __attribute__((ext_vector_type(8)));
typedef _Float16 f16x8 __attribute__((ext_vector_type(8)));
typedef float f32x4 __attribute__((ext_vector_type(4)));
typedef unsigned short u16;
typedef unsigned short u16x4 __attribute__((ext_vector_type(4)));

#define MFMA(a, b, c) __builtin_amdgcn_mfma_f32_16x16x32_bf16(a, b, c, 0, 0, 0)
#define MFMAH(a, b, c) __builtin_amdgcn_mfma_f32_16x16x32_f16(a, b, c, 0, 0, 0)

// ---------- helpers ----------
__device__ __forceinline__ u16 f2b(float f) {
    union { float f; unsigned u; } x{f};
    unsigned r = (x.u + 0x7FFFu + ((x.u >> 16) & 1u)) >> 16;
    return (u16)r;
}
__device__ __forceinline__ float b2f(u16 h) {
    union { unsigned u; float f; } x{((unsigned)h) << 16};
    return x.f;
}
__device__ __forceinline__ u16 f2h(float f) {
    _Float16 h = (_Float16)f;
    return *reinterpret_cast<u16*>(&h);
}
__device__ __forceinline__ float h2f(u16 h) {
    _Float16 v = *reinterpret_cast<_Float16*>(&h);
    return (float)v;
}
__device__ __forceinline__ float red16_sum(float v) {
#pragma unroll
    for (int m = 1; m < 16; m <<= 1) v += __shfl_xor(v, m, 64);
    return v;
}
__device__ __forceinline__ float red16_max(float v) {
#pragma unroll
    for (int m = 1; m < 16; m <<= 1) v = fmaxf(v, __shfl_xor(v, m, 64));
    return v;
}
__device__ __forceinline__ void gl_lds16(const void* g, void* l) {
    __builtin_amdgcn_global_load_lds(
        (const __attribute__((address_space(1))) unsigned int*)(g),
        (__attribute__((address_space(3))) unsigned int*)(l), 16, 0, 0);
}

// dims: B=4, C=64, N=8, V=32, W=32, D=256 ; BN=32, S=1024, tokens M=32768

// ---------- K0: weight convert: gemm weights + fragment-packed proj weights ----------
__global__ __launch_bounds__(256) void wconv_kernel(
    const float* __restrict__ W1, const float* __restrict__ W2,
    const float* __restrict__ Wo, const float* __restrict__ Win,
    const float* __restrict__ Wkv, u16* __restrict__ w1T,
    u16* __restrict__ w2T, u16* __restrict__ woT, u16* __restrict__ wfrag) {
    int id = blockIdx.x * 256 + threadIdx.x;
    if (id < 131072) {                       // W1: (256,512) -> (512,256)
        int n = id >> 8, k = id & 255;
        w1T[id] = f2b(W1[k * 512 + n]);
    } else if (id < 262144) {                // W2: (512,256) -> (256,512)
        int j = id - 131072;
        int n = j >> 9, k = j & 511;
        w2T[j] = f2b(W2[k * 256 + n]);
    } else if (id < 278528) {                // W_out: (256,64) -> (64,256)
        int j = id - 262144;
        int n = j >> 8, k = j & 255;
        woT[j] = f2b(Wo[k * 64 + n]);
    } else if (id < 284672) {                // fragment-packed proj weights (fp16)
        int fid = id - 278528;
        int arr = fid >> 11;                 // 0..2 : q, k, v
        int e = fid & 2047;
        int ntck = e >> 6, ln = e & 63;
        int lr = ln & 15, lg2 = ln >> 4;
        int nt = ntck >> 1, ck = ntck & 1;
        int d = nt * 16 + lr;
#pragma unroll
        for (int j = 0; j < 8; j++) {
            int c = ck * 32 + lg2 * 8 + j;
            float x;
            if (arr == 0)      x = Win[c * 256 + d];
            else if (arr == 1) x = Wkv[c * 512 + d];
            else               x = Wkv[c * 512 + 256 + d];
            wfrag[arr * 16384 + e * 8 + j] = f2h(x);
        }
    }
}

// ---------- K1: MFMA projection + shared LN (fp16, q/kv split across blocks) ----
// grid (16 x, 32 bn): part = x>>3 (0: lf->q, 1: hf->k,v), st = x&7.
// 512 blocks -> 2 blocks/CU (2 x 80KB LDS = exactly the 160KB pool), so the
// q-part and kv-part barrier chains overlap via co-residency.
#define PJ_A 0
#define PJ_WREG 16384
#define PJ_WORK 49152
__global__ __launch_bounds__(512, 1) void proj_kernel(
    const float* __restrict__ lf, const float* __restrict__ hf,
    const u16* __restrict__ wqg, const u16* __restrict__ wkg,
    const u16* __restrict__ wvg, const float* __restrict__ gamma,
    const float* __restrict__ beta, u16* __restrict__ qf_,
    u16* __restrict__ kf_, u16* __restrict__ vT) {
    extern __shared__ char sm[];
    const int tid = threadIdx.x;
    const int wave = tid >> 6, lane = tid & 63, lr = lane & 15, lg = lane >> 4;
    const int st = blockIdx.x & 7, part = blockIdx.x >> 3, bn = blockIdx.y;
    const int b = bn >> 3, n = bn & 7;
    const int s0 = st * 128;
    const size_t baseF = (size_t)b * 524288 + (size_t)n * 1024 + s0;

    float gam[16], bet[16];
#pragma unroll
    for (int nt = 0; nt < 16; nt++) {
        gam[nt] = gamma[nt * 16 + lr];
        bet[nt] = beta[nt * 16 + lr];
    }

    auto stage32 = [&](const float* srcbase, int chalf) {
#pragma unroll
        for (int call = 0; call < 2; call++) {
            int unit = call * 8 + wave;
            int obase = unit << 10;
            int e = unit * 256 + lane * 4;
            int cl = e >> 7, si = e & 127;
            gl_lds16(srcbase + (size_t)(chalf * 32 + cl) * 8192 + si,
                     sm + PJ_WORK + obase);
        }
    };
    auto stageW = [&](const u16* wsrc) {
#pragma unroll
        for (int call = 0; call < 4; call++) {
            int obase = (call * 8 + wave) << 10;
            gl_lds16((const char*)wsrc + obase + lane * 16, sm + PJ_WREG + obase);
        }
    };
    auto buildA = [&](int slotbase) {
        int g = wave >> 1;
        int s = ((wave & 1) << 6) | lane;
        float x[8];
#pragma unroll
        for (int cc = 0; cc < 8; cc++)
            x[cc] = *(const float*)(sm + PJ_WORK + ((g * 8 + cc) << 9) + (s << 2));
        f16x8 ph;
#pragma unroll
        for (int cc = 0; cc < 8; cc++) ph[cc] = (_Float16)x[cc];
        int slp = (slotbase + g) ^ (s & 7);
        *(f16x8*)(sm + PJ_A + (s << 7) + (slp << 4)) = ph;
    };
    auto loadA = [&](f16x8* aF) {
        int tl = wave * 16 + lr;
#pragma unroll
        for (int ck = 0; ck < 2; ck++) {
            int off = (tl << 7) + ((((ck << 2) | lg) ^ (tl & 7)) << 4);
            aF[ck] = *(const f16x8*)(sm + PJ_A + off);
        }
    };
    auto pass1 = [&](const f16x8* aF, f32x4* acc) {
#pragma unroll
        for (int nt = 0; nt < 16; nt++) acc[nt] = (f32x4){0.f, 0.f, 0.f, 0.f};
#pragma unroll
        for (int nt = 0; nt < 16; nt++) {
#pragma unroll
            for (int ck = 0; ck < 2; ck++) {
                int wo = (((nt << 1) | ck) << 10) + (lane << 4);
                f16x8 bh = *(const f16x8*)(sm + PJ_WREG + wo);
                acc[nt] = MFMAH(aF[ck], bh, acc[nt]);
            }
        }
    };
    auto lnstats = [&](const f32x4* acc, float* mean, float* rs) {
#pragma unroll
        for (int r = 0; r < 4; r++) {
            float s1 = 0.f, s2 = 0.f;
#pragma unroll
            for (int nt = 0; nt < 16; nt++) {
                float xv = acc[nt][r];
                s1 += xv; s2 += xv * xv;
            }
            s1 = red16_sum(s1);
            s2 = red16_sum(s2);
            float mn = s1 * (1.f / 256.f);
            float var = s2 * (1.f / 256.f) - mn * mn;
            mean[r] = mn;
            rs[r] = rsqrtf(var + 1e-5f);
        }
    };
    auto emit = [&](const f32x4* acc, const float* mean, const float* rs,
                    u16* dst) {
        char* bw = sm + PJ_WORK + wave * 4096;
        const int gtok = bn * 1024 + s0 + wave * 16;
#pragma unroll
        for (int hh = 0; hh < 2; hh++) {
#pragma unroll
            for (int ntl = 0; ntl < 8; ntl++) {
                int nt = hh * 8 + ntl;
#pragma unroll
                for (int r = 0; r < 4; r++) {
                    float y = (acc[nt][r] - mean[r]) * rs[r] * gam[nt] + bet[nt];
                    int tl = lg * 4 + r;
                    int dl = ntl * 16 + lr;
                    int sl = dl >> 3;
                    *(u16*)(bw + tl * 256 + ((sl ^ ((tl >> 2) & 3)) << 4) +
                            (dl & 7) * 2) = f2h(y);
                }
            }
#pragma unroll
            for (int p = 0; p < 4; p++) {
                int row = lane >> 2, slq = (lane & 3) + p * 4;
                bf16x8 v8 = *(const bf16x8*)(bw + row * 256 +
                                             ((slq ^ ((row >> 2) & 3)) << 4));
                *(bf16x8*)(dst + (size_t)(gtok + row) * 256 + hh * 128 +
                           slq * 8) = v8;
            }
        }
    };

    f32x4 acc[16];
    float mean[4], rs[4];
    f16x8 aF[2];

    if (part == 0) {
        // ---- lf -> q ----
        stage32(lf + baseF, 0);  __syncthreads();
        buildA(0);               __syncthreads();
        stage32(lf + baseF, 1);
        stageW(wqg);             __syncthreads();
        buildA(4);               __syncthreads();
        loadA(aF);
        pass1(aF, acc);
        lnstats(acc, mean, rs);
        emit(acc, mean, rs, qf_);          // bounce is wave-private; WORK free
    } else {
        // ---- hf -> k, v ----
        stage32(hf + baseF, 0);  __syncthreads();
        buildA(0);               __syncthreads();
        stage32(hf + baseF, 1);
        stageW(wkg);             __syncthreads();
        buildA(4);               __syncthreads();
        loadA(aF);
        pass1(aF, acc);
        lnstats(acc, mean, rs);  __syncthreads();   // all done reading WREG k
        stageW(wvg);                                 // overwrite WREG with v
        emit(acc, mean, rs, kf_);
        __syncthreads();                             // drains stageW + emit
        pass1(aF, acc);                              // v (same hf A-frags)
#pragma unroll
        for (int nt = 0; nt < 16; nt++) {
            u16x4 pv;
#pragma unroll
            for (int r = 0; r < 4; r++) pv[r] = f2h(acc[nt][r]);
            *(u16x4*)(vT + ((size_t)(bn * 256) + nt * 16 + lr) * 1024 + s0 +
                      wave * 16 + lg * 4) = pv;
        }
    }
}

// ---------- K2: causal flash attention, fp16, intra-block split-K ----------
// R15 configuration (race-free, 60.1us measured).
__global__ __launch_bounds__(512) void attn_kernel(
    const u16* __restrict__ qf_, const u16* __restrict__ kf_,
    const u16* __restrict__ vT, const float* __restrict__ g2,
    const float* __restrict__ b2, u16* __restrict__ lnatt) {
    extern __shared__ char smem[];
    const int tid = threadIdx.x;
    const int wave = tid >> 6, lane = tid & 63, lr = lane & 15, lg = lane >> 4;
    const int grp = wave >> 2, w4 = wave & 3;
    const int b = blockIdx.x;
    const int bn = b & 31;
    const int strip = 15 - (b >> 5);
    const int qr0 = strip * 64 + w4 * 16;
    const int ni = strip + 1;                 // iterations per group
    const int ktbase = grp * ni;
    char* myK = smem + grp * 65536;           // 2 x 16KB dbuf
    char* myV = smem + grp * 65536 + 32768;   // 2 x 16KB dbuf
    u16* Pw = (u16*)(smem + 131072 + wave * 1280);   // [16 rows][40 u16]

    f16x8 qf[8];
    {
        const size_t off = ((size_t)(bn * 1024 + qr0 + lr)) * 256 + lg * 8;
#pragma unroll
        for (int ck = 0; ck < 8; ck++)
            qf[ck] = *(const f16x8*)(qf_ + off + ck * 32);
    }
    f16x8 onesb;   // B-fragment of ones-column (row-sum via MFMA)
    {
        _Float16 v1 = (lr == 0) ? (_Float16)1.0f : (_Float16)0.0f;
#pragma unroll
        for (int q = 0; q < 8; q++) onesb[q] = v1;
    }

    const int srl = lane >> 5, ss = lane & 31;   // K staging: subrow, slot
    const int vdl = lane >> 2, vg = lane & 3;    // V staging: d-local, group
    auto stage = [&](int buf, int kt) {
        const int kv0 = kt << 5;
        char* baseK = myK + buf * 16384;
        char* baseV = myV + buf * 16384;
#pragma unroll
        for (int ii = 0; ii < 4; ii++) {
            int u = w4 * 4 + ii;                   // 0..15, 1KB units
            int r = u * 2 + srl;                   // K row 0..31
            size_t go = (((size_t)((bn << 10) + kv0 + r)) << 8) +
                        (unsigned)((ss ^ (r & 7)) << 3);
            gl_lds16(kf_ + go, baseK + u * 1024);
            int d = u * 16 + vdl;                  // V d 0..255
            size_t gv = (((size_t)((bn << 8) + d)) << 10) + kv0 +
                        (unsigned)((vg ^ ((d >> 1) & 3)) << 3);
            gl_lds16(vT + gv, baseV + u * 1024);
        }
    };

    f32x4 o[16];
#pragma unroll
    for (int i = 0; i < 16; i++) o[i] = (f32x4){0.f, 0.f, 0.f, 0.f};
    f32x4 ol = (f32x4){0.f, 0.f, 0.f, 0.f};
    float m[4] = {-INFINITY, -INFINITY, -INFINITY, -INFINITY};

    stage(0, ktbase);
    for (int it = 0; it < ni; it++) {
        const int cur = it & 1;
        asm volatile("s_waitcnt vmcnt(0)" ::: "memory");   // stage(it) landed
        __builtin_amdgcn_s_barrier();                      // compute(it-1) done
        asm volatile("" ::: "memory");
        if (it + 1 < ni) stage(cur ^ 1, ktbase + it + 1);  // overlaps compute(it)
        const int kt = ktbase + it;
        if ((kt << 5) <= qr0 + 15) {
            const char* kb = myK + cur * 16384;
            f32x4 sc0 = (f32x4){0.f, 0.f, 0.f, 0.f};
            f32x4 sc1 = (f32x4){0.f, 0.f, 0.f, 0.f};
            __builtin_amdgcn_s_setprio(1);
#pragma unroll
            for (int ck = 0; ck < 8; ck++) {
                int sw = ((ck * 4 + lg) ^ (lr & 7)) << 4;
                int a0 = lr * 512 + sw;
                f16x8 k0 = *(const f16x8*)(kb + a0);
                f16x8 k1 = *(const f16x8*)(kb + a0 + 8192);
                sc0 = MFMAH(qf[ck], k0, sc0);
                sc1 = MFMAH(qf[ck], k1, sc1);
            }
            __builtin_amdgcn_s_setprio(0);
            float scl[4];
            const int kvb = kt << 5;
#pragma unroll
            for (int r = 0; r < 4; r++) {
                int qi = qr0 + lg * 4 + r;
                float s0v = (kvb + lr > qi) ? -1e30f : sc0[r];
                float s1v = (kvb + 16 + lr > qi) ? -1e30f : sc1[r];
                float tm = red16_max(fmaxf(s0v, s1v));
                float mn = fmaxf(m[r], tm);
                scl[r] = __expf(m[r] - mn);
                m[r] = mn;
                int row = lg * 4 + r;
                Pw[row * 40 + lr] = f2h(__expf(s0v - mn));
                Pw[row * 40 + 16 + lr] = f2h(__expf(s1v - mn));
            }
#pragma unroll
            for (int f = 0; f < 16; f++) {
                f32x4 t = o[f];
                t[0] *= scl[0]; t[1] *= scl[1]; t[2] *= scl[2]; t[3] *= scl[3];
                o[f] = t;
            }
            ol[0] *= scl[0]; ol[1] *= scl[1]; ol[2] *= scl[2]; ol[3] *= scl[3];
            asm volatile("" ::: "memory");   // order P stores before pa load
            f16x8 pa = *(const f16x8*)((const char*)Pw + lr * 80 + lg * 16);
            const char* vb = myV + cur * 16384;
            __builtin_amdgcn_s_setprio(1);
#pragma unroll
            for (int db = 0; db < 16; db++) {
                int d = db * 16 + lr;
                f16x8 vf = *(const f16x8*)(vb + d * 64 +
                                           ((lg ^ ((lr >> 1) & 3)) << 4));
                o[db] = MFMAH(pa, vf, o[db]);
            }
            ol = MFMAH(pa, onesb, ol);
            __builtin_amdgcn_s_setprio(0);
        }
    }
    __syncthreads();   // loop done: protects combine's reuse of grp1 K/V LDS
    float lsum[4];
#pragma unroll
    for (int r = 0; r < 4; r++) lsum[r] = __shfl(ol[r], lane & 48, 64);

    // ---- flash-decoding combine: grp1 -> LDS, grp0 merges ----
    char* cb = smem + 65536;                 // 4 pairs x 16KB: [col][row] f32
    float* mlb = (float*)(smem + 131072);    // 64 rows x {m,l} (P region dead)
    if (grp == 1) {
        char* po = cb + w4 * 16384;
#pragma unroll
        for (int f = 0; f < 16; f++)
            *(f32x4*)(po + (f * 16 + lr) * 64 + lg * 16) = o[f];
        if (lr == 0) {
#pragma unroll
            for (int r = 0; r < 4; r++) {
                int row = lg * 4 + r;
                mlb[(w4 * 16 + row) * 2] = m[r];
                mlb[(w4 * 16 + row) * 2 + 1] = lsum[r];
            }
        }
    }
    __syncthreads();
    if (grp == 0) {
        const char* po = cb + w4 * 16384;
        float e0[4], e1[4], linv[4];
#pragma unroll
        for (int r = 0; r < 4; r++) {
            int row = lg * 4 + r;
            float m1 = mlb[(w4 * 16 + row) * 2];
            float l1 = mlb[(w4 * 16 + row) * 2 + 1];
            float ms = fmaxf(m[r], m1);
            e0[r] = __expf(m[r] - ms);
            e1[r] = __expf(m1 - ms);
            linv[r] = 1.f / (lsum[r] * e0[r] + l1 * e1[r]);
        }
#pragma unroll
        for (int f = 0; f < 16; f++) {
            f32x4 o1 = *(const f32x4*)(po + (f * 16 + lr) * 64 + lg * 16);
#pragma unroll
            for (int r = 0; r < 4; r++)
                o[f][r] = (o[f][r] * e0[r] + o1[r] * e1[r]) * linv[r];
        }
        float gv[16], bv[16];
#pragma unroll
        for (int f = 0; f < 16; f++) {
            gv[f] = g2[f * 16 + lr];
            bv[f] = b2[f * 16 + lr];
        }
#pragma unroll
        for (int r = 0; r < 4; r++) {
            float s1 = 0.f, s2 = 0.f;
#pragma unroll
            for (int f = 0; f < 16; f++) {
                float x = o[f][r];
                s1 += x; s2 += x * x;
            }
            s1 = red16_sum(s1);
            s2 = red16_sum(s2);
            float mean = s1 * (1.f / 256.f);
            float var = s2 * (1.f / 256.f) - mean * mean;
            float rsv = rsqrtf(var + 1e-5f);
            size_t row = (size_t)(bn * 1024 + qr0 + lg * 4 + r) * 256;
#pragma unroll
            for (int f = 0; f < 16; f++)
                lnatt[row + f * 16 + lr] =
                    f2b((o[f][r] - mean) * rsv * gv[f] + bv[f]);
        }
    }
}

// ---------- K3/K4/K5: LDS-staged GEMM, A(MxK) bf16, BT(NxK) bf16 ----------
template <int K, int NB, int MODE>
__global__ __launch_bounds__(512) void gemmB_kernel(
    const u16* __restrict__ A, const u16* __restrict__ BT,
    u16* __restrict__ outb, const u16* __restrict__ vTr,
    float* __restrict__ outf, int ldOut) {
    extern __shared__ char bsm[];
    const int tid = threadIdx.x;
    const int wave = tid >> 6, lane = tid & 63, lr = lane & 15, lg = lane >> 4;
    constexpr int K2 = K * 2;           // bytes per B column
    constexpr int BN = NB * 16;
    constexpr int TILE = BN * K2;
    const int m0 = blockIdx.x * 128 + wave * 16;
    const int n0 = blockIdx.y * BN;
    {
        const char* bsrc = (const char*)(BT + (size_t)n0 * K);
        constexpr int ITER = TILE / (512 * 16);
#pragma unroll
        for (int it = 0; it < ITER; it++) {
            int o = (it * 512 + tid) * 16;
            int col = o / K2;
            int slot = (o % K2) >> 4;
            int src = col * K2 + ((slot ^ (col & 7)) << 4);
            gl_lds16(bsrc + src, bsm + o);
        }
    }
    __syncthreads();
    f32x4 acc[NB];
#pragma unroll
    for (int nb = 0; nb < NB; nb++) acc[nb] = (f32x4){0.f, 0.f, 0.f, 0.f};
    const u16* ap = A + (size_t)(m0 + lr) * K + lg * 8;
#pragma unroll
    for (int kc = 0; kc < K; kc += 32) {
        bf16x8 a = *(const bf16x8*)(ap + kc);
        int ks = (kc >> 3) + lg;
#pragma unroll
        for (int nb = 0; nb < NB; nb++) {
            int c = nb * 16 + lr;
            bf16x8 bv = *(const bf16x8*)(bsm + c * K2 + ((ks ^ (c & 7)) << 4));
            acc[nb] = MFMA(a, bv, acc[nb]);
        }
    }
    const int g = m0 + lg * 4;
    if (MODE == 0) {
#pragma unroll
        for (int nb = 0; nb < NB; nb++)
#pragma unroll
            for (int r = 0; r < 4; r++)
                outb[(size_t)(g + r) * ldOut + n0 + nb * 16 + lr] =
                    f2b(fmaxf(acc[nb][r], 0.f));
    } else if (MODE == 1) {
        int bn = g >> 10, s = g & 1023;
#pragma unroll
        for (int nb = 0; nb < NB; nb++) {
            int dd = n0 + nb * 16 + lr;
            u16x4 vv = *(const u16x4*)(vTr + ((size_t)bn * 256 + dd) * 1024 + s);
#pragma unroll
            for (int r = 0; r < 4; r++)
                outb[(size_t)(g + r) * 256 + dd] = f2b(acc[nb][r] + h2f(vv[r]));
        }
    } else {
        int bn = g >> 10, s = g & 1023;
        int bb = bn >> 3, nn = bn & 7;
#pragma unroll
        for (int nb = 0; nb < NB; nb++) {
            int cc = n0 + nb * 16 + lr;
            *(f32x4*)(outf + (size_t)bb * 524288 + (size_t)cc * 8192 +
                      (size_t)nn * 1024 + s) = acc[nb];
        }
    }
}

extern "C" void kernel_launch(void* const* d_in, const int* in_sizes, int n_in,
                              void* d_out, int out_size, void* d_ws, size_t ws_size,
                              hipStream_t stream) {
    const float* lf    = (const float*)d_in[0];
    const float* hf    = (const float*)d_in[1];
    const float* Win   = (const float*)d_in[2];
    const float* Wkv   = (const float*)d_in[3];
    const float* gamma = (const float*)d_in[4];
    const float* beta  = (const float*)d_in[5];
    const float* g2    = (const float*)d_in[6];
    const float* b2    = (const float*)d_in[7];
    const float* W1    = (const float*)d_in[8];
    const float* W2    = (const float*)d_in[9];
    const float* Wo    = (const float*)d_in[10];
    float* out = (float*)d_out;

    char* w = (char*)d_ws;
    const size_t MB16 = 16777216;
    u16* qf  = (u16*)(w);                        // fp16 q (16.78 MB)
    u16* kf  = (u16*)(w + MB16);                 // fp16 k
    u16* vT  = (u16*)(w + 2 * MB16);             // fp16 v, (BN,256,1024)
    u16* hb  = (u16*)(w + 3 * MB16);             // bf16 FFN hidden (33.55 MB)
    u16* w1T = (u16*)(w + 3 * MB16 + 33554432);
    u16* w2T = w1T + 131072;
    u16* woT = w2T + 131072;
    u16* wfrag = woT + 16384;                    // 3 x 16384 u16 (fp16)
    u16* wqg = wfrag;
    u16* wkg = wfrag + 16384;
    u16* wvg = wfrag + 32768;
    u16* lnatt = qf;   // reuse: q rows consumed before LN write (bf16)
    u16* epib  = kf;   // reuse: k dead after attention (bf16)

    wconv_kernel<<<dim3(1136), dim3(256), 0, stream>>>(W1, W2, Wo, Win, Wkv,
                                                       w1T, w2T, woT, wfrag);
    proj_kernel<<<dim3(16, 32), dim3(512), 81920, stream>>>(
        lf, hf, wqg, wkg, wvg, gamma, beta, qf, kf, vT);
    attn_kernel<<<dim3(512), dim3(512), 141312, stream>>>(qf, kf, vT, g2, b2,
                                                          lnatt);
    gemmB_kernel<256, 8, 0><<<dim3(256, 4), dim3(512), 65536, stream>>>(
        lnatt, w1T, hb, nullptr, nullptr, 512);
    gemmB_kernel<512, 8, 1><<<dim3(256, 2), dim3(512), 131072, stream>>>(
        hb, w2T, epib, vT, nullptr, 256);
    gemmB_kernel<256, 4, 2><<<dim3(256, 1), dim3(512), 32768, stream>>>(
        epib, woT, nullptr, nullptr, out, 64);
}

// Round 19
// 128.620 us; speedup vs baseline: 1.0546x; 1.0307x over previous
//
#include <hip/hip_runtime.h>

typedef short bf16x8 __attribute__((ext_vector_type(8)));
typedef _Float16 f16x8 __attribute__((ext_vector_type(8)));
typedef float f32x4 __attribute__((ext_vector_type(4)));
typedef unsigned short u16;
typedef unsigned short u16x4 __attribute__((ext_vector_type(4)));

#define MFMA(a, b, c) __builtin_amdgcn_mfma_f32_16x16x32_bf16(a, b, c, 0, 0, 0)
#define MFMAH(a, b, c) __builtin_amdgcn_mfma_f32_16x16x32_f16(a, b, c, 0, 0, 0)

// ---------- helpers ----------
__device__ __forceinline__ u16 f2b(float f) {
    union { float f; unsigned u; } x{f};
    unsigned r = (x.u + 0x7FFFu + ((x.u >> 16) & 1u)) >> 16;
    return (u16)r;
}
__device__ __forceinline__ float b2f(u16 h) {
    union { unsigned u; float f; } x{((unsigned)h) << 16};
    return x.f;
}
__device__ __forceinline__ u16 f2h(float f) {
    _Float16 h = (_Float16)f;
    return *reinterpret_cast<u16*>(&h);
}
__device__ __forceinline__ float h2f(u16 h) {
    _Float16 v = *reinterpret_cast<_Float16*>(&h);
    return (float)v;
}
__device__ __forceinline__ float red16_sum(float v) {
#pragma unroll
    for (int m = 1; m < 16; m <<= 1) v += __shfl_xor(v, m, 64);
    return v;
}
__device__ __forceinline__ float red16_max(float v) {
#pragma unroll
    for (int m = 1; m < 16; m <<= 1) v = fmaxf(v, __shfl_xor(v, m, 64));
    return v;
}
__device__ __forceinline__ void gl_lds16(const void* g, void* l) {
    __builtin_amdgcn_global_load_lds(
        (const __attribute__((address_space(1))) unsigned int*)(g),
        (__attribute__((address_space(3))) unsigned int*)(l), 16, 0, 0);
}

// dims: B=4, C=64, N=8, V=32, W=32, D=256 ; BN=32, S=1024, tokens M=32768

// ---------- K0: weight convert: gemm weights + fragment-packed proj weights ----------
__global__ __launch_bounds__(256) void wconv_kernel(
    const float* __restrict__ W1, const float* __restrict__ W2,
    const float* __restrict__ Wo, const float* __restrict__ Win,
    const float* __restrict__ Wkv, u16* __restrict__ w1T,
    u16* __restrict__ w2T, u16* __restrict__ woT, u16* __restrict__ wfrag) {
    int id = blockIdx.x * 256 + threadIdx.x;
    if (id < 131072) {                       // W1: (256,512) -> (512,256)
        int n = id >> 8, k = id & 255;
        w1T[id] = f2b(W1[k * 512 + n]);
    } else if (id < 262144) {                // W2: (512,256) -> (256,512)
        int j = id - 131072;
        int n = j >> 9, k = j & 511;
        w2T[j] = f2b(W2[k * 256 + n]);
    } else if (id < 278528) {                // W_out: (256,64) -> (64,256)
        int j = id - 262144;
        int n = j >> 8, k = j & 255;
        woT[j] = f2b(Wo[k * 64 + n]);
    } else if (id < 284672) {                // fragment-packed proj weights (fp16)
        int fid = id - 278528;
        int arr = fid >> 11;                 // 0..2 : q, k, v
        int e = fid & 2047;
        int ntck = e >> 6, ln = e & 63;
        int lr = ln & 15, lg2 = ln >> 4;
        int nt = ntck >> 1, ck = ntck & 1;
        int d = nt * 16 + lr;
#pragma unroll
        for (int j = 0; j < 8; j++) {
            int c = ck * 32 + lg2 * 8 + j;
            float x;
            if (arr == 0)      x = Win[c * 256 + d];
            else if (arr == 1) x = Wkv[c * 512 + d];
            else               x = Wkv[c * 512 + 256 + d];
            wfrag[arr * 16384 + e * 8 + j] = f2h(x);
        }
    }
}

// ---------- K1: MFMA projection + shared LN (fp16, combined, 64KB LDS) ----------
// grid (8 st, 32 bn), 512 threads = 8 waves. LDS 64KB -> 2 blocks/CU:
// A 0..16K (fp16 A-frags; DEAD after loadA -> reused as emit bounce for
// waves 0-3); WREG 16..48K (fp16 weight frags); WORK 48..64K (fp32 staging;
// reused as emit bounce for waves 4-7). Same barrier chain as R15 —
// every bounce write is after a barrier retiring loadA/buildA reads, every
// staging overwrite is after the barrier draining emit.
#define PJ_A 0
#define PJ_WREG 16384
#define PJ_WORK 49152
__global__ __launch_bounds__(512, 1) void proj_kernel(
    const float* __restrict__ lf, const float* __restrict__ hf,
    const u16* __restrict__ wqg, const u16* __restrict__ wkg,
    const u16* __restrict__ wvg, const float* __restrict__ gamma,
    const float* __restrict__ beta, u16* __restrict__ qf_,
    u16* __restrict__ kf_, u16* __restrict__ vT) {
    extern __shared__ char sm[];
    const int tid = threadIdx.x;
    const int wave = tid >> 6, lane = tid & 63, lr = lane & 15, lg = lane >> 4;
    const int st = blockIdx.x, bn = blockIdx.y;
    const int b = bn >> 3, n = bn & 7;
    const int s0 = st * 128;
    const size_t baseF = (size_t)b * 524288 + (size_t)n * 1024 + s0;

    float gam[16], bet[16];
#pragma unroll
    for (int nt = 0; nt < 16; nt++) {
        gam[nt] = gamma[nt * 16 + lr];
        bet[nt] = beta[nt * 16 + lr];
    }

    auto stage32 = [&](const float* srcbase, int chalf) {
#pragma unroll
        for (int call = 0; call < 2; call++) {
            int unit = call * 8 + wave;
            int obase = unit << 10;
            int e = unit * 256 + lane * 4;
            int cl = e >> 7, si = e & 127;
            gl_lds16(srcbase + (size_t)(chalf * 32 + cl) * 8192 + si,
                     sm + PJ_WORK + obase);
        }
    };
    auto stageW = [&](const u16* wsrc) {
#pragma unroll
        for (int call = 0; call < 4; call++) {
            int obase = (call * 8 + wave) << 10;
            gl_lds16((const char*)wsrc + obase + lane * 16, sm + PJ_WREG + obase);
        }
    };
    auto buildA = [&](int slotbase) {
        int g = wave >> 1;
        int s = ((wave & 1) << 6) | lane;
        float x[8];
#pragma unroll
        for (int cc = 0; cc < 8; cc++)
            x[cc] = *(const float*)(sm + PJ_WORK + ((g * 8 + cc) << 9) + (s << 2));
        f16x8 ph;
#pragma unroll
        for (int cc = 0; cc < 8; cc++) ph[cc] = (_Float16)x[cc];
        int slp = (slotbase + g) ^ (s & 7);
        *(f16x8*)(sm + PJ_A + (s << 7) + (slp << 4)) = ph;
    };
    auto loadA = [&](f16x8* aF) {
        int tl = wave * 16 + lr;
#pragma unroll
        for (int ck = 0; ck < 2; ck++) {
            int off = (tl << 7) + ((((ck << 2) | lg) ^ (tl & 7)) << 4);
            aF[ck] = *(const f16x8*)(sm + PJ_A + off);
        }
    };
    auto pass1 = [&](const f16x8* aF, f32x4* acc) {
#pragma unroll
        for (int nt = 0; nt < 16; nt++) acc[nt] = (f32x4){0.f, 0.f, 0.f, 0.f};
#pragma unroll
        for (int nt = 0; nt < 16; nt++) {
#pragma unroll
            for (int ck = 0; ck < 2; ck++) {
                int wo = (((nt << 1) | ck) << 10) + (lane << 4);
                f16x8 bh = *(const f16x8*)(sm + PJ_WREG + wo);
                acc[nt] = MFMAH(aF[ck], bh, acc[nt]);
            }
        }
    };
    auto lnstats = [&](const f32x4* acc, float* mean, float* rs) {
#pragma unroll
        for (int r = 0; r < 4; r++) {
            float s1 = 0.f, s2 = 0.f;
#pragma unroll
            for (int nt = 0; nt < 16; nt++) {
                float xv = acc[nt][r];
                s1 += xv; s2 += xv * xv;
            }
            s1 = red16_sum(s1);
            s2 = red16_sum(s2);
            float mn = s1 * (1.f / 256.f);
            float var = s2 * (1.f / 256.f) - mn * mn;
            mean[r] = mn;
            rs[r] = rsqrtf(var + 1e-5f);
        }
    };
    // emit bounce: waves 0-3 use the (dead) A region, waves 4-7 use WORK.
    auto emit = [&](const f32x4* acc, const float* mean, const float* rs,
                    u16* dst) {
        char* bw = sm + ((wave < 4) ? (wave * 4096)
                                    : (PJ_WORK + (wave - 4) * 4096));
        const int gtok = bn * 1024 + s0 + wave * 16;
#pragma unroll
        for (int hh = 0; hh < 2; hh++) {
#pragma unroll
            for (int ntl = 0; ntl < 8; ntl++) {
                int nt = hh * 8 + ntl;
#pragma unroll
                for (int r = 0; r < 4; r++) {
                    float y = (acc[nt][r] - mean[r]) * rs[r] * gam[nt] + bet[nt];
                    int tl = lg * 4 + r;
                    int dl = ntl * 16 + lr;
                    int sl = dl >> 3;
                    *(u16*)(bw + tl * 256 + ((sl ^ ((tl >> 2) & 3)) << 4) +
                            (dl & 7) * 2) = f2h(y);
                }
            }
#pragma unroll
            for (int p = 0; p < 4; p++) {
                int row = lane >> 2, slq = (lane & 3) + p * 4;
                bf16x8 v8 = *(const bf16x8*)(bw + row * 256 +
                                             ((slq ^ ((row >> 2) & 3)) << 4));
                *(bf16x8*)(dst + (size_t)(gtok + row) * 256 + hh * 128 +
                           slq * 8) = v8;
            }
        }
    };

    f32x4 acc[16];
    float mean[4], rs[4];
    f16x8 aF[2];

    // ---- lf -> q ----
    stage32(lf + baseF, 0);  __syncthreads();     // P0
    buildA(0);               __syncthreads();     // P1
    stage32(lf + baseF, 1);
    stageW(wqg);             __syncthreads();     // P2
    buildA(4);               __syncthreads();     // P3
    loadA(aF);
    pass1(aF, acc);
    lnstats(acc, mean, rs);  __syncthreads();     // P4 (loadA/WREG reads done)
    stageW(wkg);                                  // P5: overwrite WREG w/ k
    emit(acc, mean, rs, qf_);                     // bounce in dead A/WORK
    __syncthreads();                              // drains stageW + emit
    // ---- hf -> k, v ----
    stage32(hf + baseF, 0);  __syncthreads();     // P6
    buildA(0);               __syncthreads();     // P7
    stage32(hf + baseF, 1);  __syncthreads();     // P8
    buildA(4);               __syncthreads();     // P9
    loadA(aF);
    pass1(aF, acc);
    lnstats(acc, mean, rs);  __syncthreads();     // P10 (A dead from here on)
    stageW(wvg);                                  // P11: overwrite WREG w/ v
    emit(acc, mean, rs, kf_);
    __syncthreads();                              // drains stageW + emit
    pass1(aF, acc);                               // P12: v (registers + WREG)
#pragma unroll
    for (int nt = 0; nt < 16; nt++) {
        u16x4 pv;
#pragma unroll
        for (int r = 0; r < 4; r++) pv[r] = f2h(acc[nt][r]);
        *(u16x4*)(vT + ((size_t)(bn * 256) + nt * 16 + lr) * 1024 + s0 +
                  wave * 16 + lg * 4) = pv;
    }
}

// ---------- K2: causal flash attention, fp16, intra-block split-K ----------
// R15 configuration (race-free, 60.1us measured).
__global__ __launch_bounds__(512) void attn_kernel(
    const u16* __restrict__ qf_, const u16* __restrict__ kf_,
    const u16* __restrict__ vT, const float* __restrict__ g2,
    const float* __restrict__ b2, u16* __restrict__ lnatt) {
    extern __shared__ char smem[];
    const int tid = threadIdx.x;
    const int wave = tid >> 6, lane = tid & 63, lr = lane & 15, lg = lane >> 4;
    const int grp = wave >> 2, w4 = wave & 3;
    const int b = blockIdx.x;
    const int bn = b & 31;
    const int strip = 15 - (b >> 5);
    const int qr0 = strip * 64 + w4 * 16;
    const int ni = strip + 1;                 // iterations per group
    const int ktbase = grp * ni;
    char* myK = smem + grp * 65536;           // 2 x 16KB dbuf
    char* myV = smem + grp * 65536 + 32768;   // 2 x 16KB dbuf
    u16* Pw = (u16*)(smem + 131072 + wave * 1280);   // [16 rows][40 u16]

    f16x8 qf[8];
    {
        const size_t off = ((size_t)(bn * 1024 + qr0 + lr)) * 256 + lg * 8;
#pragma unroll
        for (int ck = 0; ck < 8; ck++)
            qf[ck] = *(const f16x8*)(qf_ + off + ck * 32);
    }
    f16x8 onesb;   // B-fragment of ones-column (row-sum via MFMA)
    {
        _Float16 v1 = (lr == 0) ? (_Float16)1.0f : (_Float16)0.0f;
#pragma unroll
        for (int q = 0; q < 8; q++) onesb[q] = v1;
    }

    const int srl = lane >> 5, ss = lane & 31;   // K staging: subrow, slot
    const int vdl = lane >> 2, vg = lane & 3;    // V staging: d-local, group
    auto stage = [&](int buf, int kt) {
        const int kv0 = kt << 5;
        char* baseK = myK + buf * 16384;
        char* baseV = myV + buf * 16384;
#pragma unroll
        for (int ii = 0; ii < 4; ii++) {
            int u = w4 * 4 + ii;                   // 0..15, 1KB units
            int r = u * 2 + srl;                   // K row 0..31
            size_t go = (((size_t)((bn << 10) + kv0 + r)) << 8) +
                        (unsigned)((ss ^ (r & 7)) << 3);
            gl_lds16(kf_ + go, baseK + u * 1024);
            int d = u * 16 + vdl;                  // V d 0..255
            size_t gv = (((size_t)((bn << 8) + d)) << 10) + kv0 +
                        (unsigned)((vg ^ ((d >> 1) & 3)) << 3);
            gl_lds16(vT + gv, baseV + u * 1024);
        }
    };

    f32x4 o[16];
#pragma unroll
    for (int i = 0; i < 16; i++) o[i] = (f32x4){0.f, 0.f, 0.f, 0.f};
    f32x4 ol = (f32x4){0.f, 0.f, 0.f, 0.f};
    float m[4] = {-INFINITY, -INFINITY, -INFINITY, -INFINITY};

    stage(0, ktbase);
    for (int it = 0; it < ni; it++) {
        const int cur = it & 1;
        asm volatile("s_waitcnt vmcnt(0)" ::: "memory");   // stage(it) landed
        __builtin_amdgcn_s_barrier();                      // compute(it-1) done
        asm volatile("" ::: "memory");
        if (it + 1 < ni) stage(cur ^ 1, ktbase + it + 1);  // overlaps compute(it)
        const int kt = ktbase + it;
        if ((kt << 5) <= qr0 + 15) {
            const char* kb = myK + cur * 16384;
            f32x4 sc0 = (f32x4){0.f, 0.f, 0.f, 0.f};
            f32x4 sc1 = (f32x4){0.f, 0.f, 0.f, 0.f};
            __builtin_amdgcn_s_setprio(1);
#pragma unroll
            for (int ck = 0; ck < 8; ck++) {
                int sw = ((ck * 4 + lg) ^ (lr & 7)) << 4;
                int a0 = lr * 512 + sw;
                f16x8 k0 = *(const f16x8*)(kb + a0);
                f16x8 k1 = *(const f16x8*)(kb + a0 + 8192);
                sc0 = MFMAH(qf[ck], k0, sc0);
                sc1 = MFMAH(qf[ck], k1, sc1);
            }
            __builtin_amdgcn_s_setprio(0);
            float scl[4];
            const int kvb = kt << 5;
#pragma unroll
            for (int r = 0; r < 4; r++) {
                int qi = qr0 + lg * 4 + r;
                float s0v = (kvb + lr > qi) ? -1e30f : sc0[r];
                float s1v = (kvb + 16 + lr > qi) ? -1e30f : sc1[r];
                float tm = red16_max(fmaxf(s0v, s1v));
                float mn = fmaxf(m[r], tm);
                scl[r] = __expf(m[r] - mn);
                m[r] = mn;
                int row = lg * 4 + r;
                Pw[row * 40 + lr] = f2h(__expf(s0v - mn));
                Pw[row * 40 + 16 + lr] = f2h(__expf(s1v - mn));
            }
#pragma unroll
            for (int f = 0; f < 16; f++) {
                f32x4 t = o[f];
                t[0] *= scl[0]; t[1] *= scl[1]; t[2] *= scl[2]; t[3] *= scl[3];
                o[f] = t;
            }
            ol[0] *= scl[0]; ol[1] *= scl[1]; ol[2] *= scl[2]; ol[3] *= scl[3];
            asm volatile("" ::: "memory");   // order P stores before pa load
            f16x8 pa = *(const f16x8*)((const char*)Pw + lr * 80 + lg * 16);
            const char* vb = myV + cur * 16384;
            __builtin_amdgcn_s_setprio(1);
#pragma unroll
            for (int db = 0; db < 16; db++) {
                int d = db * 16 + lr;
                f16x8 vf = *(const f16x8*)(vb + d * 64 +
                                           ((lg ^ ((lr >> 1) & 3)) << 4));
                o[db] = MFMAH(pa, vf, o[db]);
            }
            ol = MFMAH(pa, onesb, ol);
            __builtin_amdgcn_s_setprio(0);
        }
    }
    __syncthreads();   // loop done: protects combine's reuse of grp1 K/V LDS
    float lsum[4];
#pragma unroll
    for (int r = 0; r < 4; r++) lsum[r] = __shfl(ol[r], lane & 48, 64);

    // ---- flash-decoding combine: grp1 -> LDS, grp0 merges ----
    char* cb = smem + 65536;                 // 4 pairs x 16KB: [col][row] f32
    float* mlb = (float*)(smem + 131072);    // 64 rows x {m,l} (P region dead)
    if (grp == 1) {
        char* po = cb + w4 * 16384;
#pragma unroll
        for (int f = 0; f < 16; f++)
            *(f32x4*)(po + (f * 16 + lr) * 64 + lg * 16) = o[f];
        if (lr == 0) {
#pragma unroll
            for (int r = 0; r < 4; r++) {
                int row = lg * 4 + r;
                mlb[(w4 * 16 + row) * 2] = m[r];
                mlb[(w4 * 16 + row) * 2 + 1] = lsum[r];
            }
        }
    }
    __syncthreads();
    if (grp == 0) {
        const char* po = cb + w4 * 16384;
        float e0[4], e1[4], linv[4];
#pragma unroll
        for (int r = 0; r < 4; r++) {
            int row = lg * 4 + r;
            float m1 = mlb[(w4 * 16 + row) * 2];
            float l1 = mlb[(w4 * 16 + row) * 2 + 1];
            float ms = fmaxf(m[r], m1);
            e0[r] = __expf(m[r] - ms);
            e1[r] = __expf(m1 - ms);
            linv[r] = 1.f / (lsum[r] * e0[r] + l1 * e1[r]);
        }
#pragma unroll
        for (int f = 0; f < 16; f++) {
            f32x4 o1 = *(const f32x4*)(po + (f * 16 + lr) * 64 + lg * 16);
#pragma unroll
            for (int r = 0; r < 4; r++)
                o[f][r] = (o[f][r] * e0[r] + o1[r] * e1[r]) * linv[r];
        }
        float gv[16], bv[16];
#pragma unroll
        for (int f = 0; f < 16; f++) {
            gv[f] = g2[f * 16 + lr];
            bv[f] = b2[f * 16 + lr];
        }
#pragma unroll
        for (int r = 0; r < 4; r++) {
            float s1 = 0.f, s2 = 0.f;
#pragma unroll
            for (int f = 0; f < 16; f++) {
                float x = o[f][r];
                s1 += x; s2 += x * x;
            }
            s1 = red16_sum(s1);
            s2 = red16_sum(s2);
            float mean = s1 * (1.f / 256.f);
            float var = s2 * (1.f / 256.f) - mean * mean;
            float rsv = rsqrtf(var + 1e-5f);
            size_t row = (size_t)(bn * 1024 + qr0 + lg * 4 + r) * 256;
#pragma unroll
            for (int f = 0; f < 16; f++)
                lnatt[row + f * 16 + lr] =
                    f2b((o[f][r] - mean) * rsv * gv[f] + bv[f]);
        }
    }
}

// ---------- K3/K4/K5: LDS-staged GEMM, A(MxK) bf16, BT(NxK) bf16 ----------
template <int K, int NB, int MODE>
__global__ __launch_bounds__(512) void gemmB_kernel(
    const u16* __restrict__ A, const u16* __restrict__ BT,
    u16* __restrict__ outb, const u16* __restrict__ vTr,
    float* __restrict__ outf, int ldOut) {
    extern __shared__ char bsm[];
    const int tid = threadIdx.x;
    const int wave = tid >> 6, lane = tid & 63, lr = lane & 15, lg = lane >> 4;
    constexpr int K2 = K * 2;           // bytes per B column
    constexpr int BN = NB * 16;
    constexpr int TILE = BN * K2;
    const int m0 = blockIdx.x * 128 + wave * 16;
    const int n0 = blockIdx.y * BN;
    {
        const char* bsrc = (const char*)(BT + (size_t)n0 * K);
        constexpr int ITER = TILE / (512 * 16);
#pragma unroll
        for (int it = 0; it < ITER; it++) {
            int o = (it * 512 + tid) * 16;
            int col = o / K2;
            int slot = (o % K2) >> 4;
            int src = col * K2 + ((slot ^ (col & 7)) << 4);
            gl_lds16(bsrc + src, bsm + o);
        }
    }
    __syncthreads();
    f32x4 acc[NB];
#pragma unroll
    for (int nb = 0; nb < NB; nb++) acc[nb] = (f32x4){0.f, 0.f, 0.f, 0.f};
    const u16* ap = A + (size_t)(m0 + lr) * K + lg * 8;
#pragma unroll
    for (int kc = 0; kc < K; kc += 32) {
        bf16x8 a = *(const bf16x8*)(ap + kc);
        int ks = (kc >> 3) + lg;
#pragma unroll
        for (int nb = 0; nb < NB; nb++) {
            int c = nb * 16 + lr;
            bf16x8 bv = *(const bf16x8*)(bsm + c * K2 + ((ks ^ (c & 7)) << 4));
            acc[nb] = MFMA(a, bv, acc[nb]);
        }
    }
    const int g = m0 + lg * 4;
    if (MODE == 0) {
#pragma unroll
        for (int nb = 0; nb < NB; nb++)
#pragma unroll
            for (int r = 0; r < 4; r++)
                outb[(size_t)(g + r) * ldOut + n0 + nb * 16 + lr] =
                    f2b(fmaxf(acc[nb][r], 0.f));
    } else if (MODE == 1) {
        int bn = g >> 10, s = g & 1023;
#pragma unroll
        for (int nb = 0; nb < NB; nb++) {
            int dd = n0 + nb * 16 + lr;
            u16x4 vv = *(const u16x4*)(vTr + ((size_t)bn * 256 + dd) * 1024 + s);
#pragma unroll
            for (int r = 0; r < 4; r++)
                outb[(size_t)(g + r) * 256 + dd] = f2b(acc[nb][r] + h2f(vv[r]));
        }
    } else {
        int bn = g >> 10, s = g & 1023;
        int bb = bn >> 3, nn = bn & 7;
#pragma unroll
        for (int nb = 0; nb < NB; nb++) {
            int cc = n0 + nb * 16 + lr;
            *(f32x4*)(outf + (size_t)bb * 524288 + (size_t)cc * 8192 +
                      (size_t)nn * 1024 + s) = acc[nb];
        }
    }
}

extern "C" void kernel_launch(void* const* d_in, const int* in_sizes, int n_in,
                              void* d_out, int out_size, void* d_ws, size_t ws_size,
                              hipStream_t stream) {
    const float* lf    = (const float*)d_in[0];
    const float* hf    = (const float*)d_in[1];
    const float* Win   = (const float*)d_in[2];
    const float* Wkv   = (const float*)d_in[3];
    const float* gamma = (const float*)d_in[4];
    const float* beta  = (const float*)d_in[5];
    const float* g2    = (const float*)d_in[6];
    const float* b2    = (const float*)d_in[7];
    const float* W1    = (const float*)d_in[8];
    const float* W2    = (const float*)d_in[9];
    const float* Wo    = (const float*)d_in[10];
    float* out = (float*)d_out;

    char* w = (char*)d_ws;
    const size_t MB16 = 16777216;
    u16* qf  = (u16*)(w);                        // fp16 q (16.78 MB)
    u16* kf  = (u16*)(w + MB16);                 // fp16 k
    u16* vT  = (u16*)(w + 2 * MB16);             // fp16 v, (BN,256,1024)
    u16* hb  = (u16*)(w + 3 * MB16);             // bf16 FFN hidden (33.55 MB)
    u16* w1T = (u16*)(w + 3 * MB16 + 33554432);
    u16* w2T = w1T + 131072;
    u16* woT = w2T + 131072;
    u16* wfrag = woT + 16384;                    // 3 x 16384 u16 (fp16)
    u16* wqg = wfrag;
    u16* wkg = wfrag + 16384;
    u16* wvg = wfrag + 32768;
    u16* lnatt = qf;   // reuse: q rows consumed before LN write (bf16)
    u16* epib  = kf;   // reuse: k dead after attention (bf16)

    wconv_kernel<<<dim3(1136), dim3(256), 0, stream>>>(W1, W2, Wo, Win, Wkv,
                                                       w1T, w2T, woT, wfrag);
    proj_kernel<<<dim3(8, 32), dim3(512), 65536, stream>>>(
        lf, hf, wqg, wkg, wvg, gamma, beta, qf, kf, vT);
    attn_kernel<<<dim3(512), dim3(512), 141312, stream>>>(qf, kf, vT, g2, b2,
                                                          lnatt);
    gemmB_kernel<256, 8, 0><<<dim3(256, 4), dim3(512), 65536, stream>>>(
        lnatt, w1T, hb, nullptr, nullptr, 512);
    gemmB_kernel<512, 8, 1><<<dim3(256, 2), dim3(512), 131072, stream>>>(
        hb, w2T, epib, vT, nullptr, 256);
    gemmB_kernel<256, 4, 2><<<dim3(256, 1), dim3(512), 32768, stream>>>(
        epib, woT, nullptr, nullptr, out, 64);
}